// Round 1
// 1044.124 us; speedup vs baseline: 1.1868x; 1.1868x over previous
//
#include <hip/hip_runtime.h>
#include <hip/hip_bf16.h>
#include <stdint.h>

#define NN 50000
#define NE 400000
#define FN 32
#define FE 16
#define FG 16
#define H1 256
#define H2 128
#define M2 (2*NN)          // concatenated [in-counts, out-counts]
#define SCAN_B 391         // ceil(M2/256)
#define LCAP 1536          // staged edge-list capacity per tile per direction

typedef unsigned short u16;
typedef __bf16 bfv8 __attribute__((ext_vector_type(8)));
typedef float f32v4 __attribute__((ext_vector_type(4)));
typedef u16 usv2 __attribute__((ext_vector_type(2)));
typedef u16 usv4 __attribute__((ext_vector_type(4)));
typedef u16 usv8 __attribute__((ext_vector_type(8)));

#define APK 264   // LDS pitch (bf16 elems): 528B rows (node1: K=256 tiles)
#define AP2 136   // LDS pitch for node2's K=128 tiles: 272B rows, 16B-aligned frag reads
#define EP1 40    // LDS pitch for edge1's 64x32 tile (80B rows, 16B-aligned frag reads)

__device__ __forceinline__ u16 f2b(float x){
  __hip_bfloat16 h = __float2bfloat16(x);
  return *reinterpret_cast<u16*>(&h);
}
__device__ __forceinline__ float bf2f(u16 u){
  union{uint32_t i; float f;} v; v.i = ((uint32_t)u) << 16; return v.f;
}

// ---------------- MFMA GEMM over LDS A-tile [row][k] and frag-packed B ----------------
// B packed: dst[((ck*NNT+nt)*64 + lane)*8 + j] = bf16(B[ck*32 + (lane>>4)*8 + j][nt*16 + (lane&15)])
template<int NCK, int NNT, int PITCH>
__device__ __forceinline__ void gemm_tiles(const u16* a_s, const u16* __restrict__ pB,
                                           int w, int l, f32v4* acc)
{
  const int lr = l & 15, q = l >> 4;
  const bfv8* bp = (const bfv8*)pB;
  for (int ck = 0; ck < NCK; ck++){
    bfv8 a = *(const bfv8*)&a_s[(w*16 + lr)*PITCH + ck*32 + q*8];
    #pragma unroll
    for (int nt = 0; nt < NNT; nt++){
      bfv8 b = bp[(ck*NNT + nt)*64 + l];
      acc[nt] = __builtin_amdgcn_mfma_f32_16x16x32_bf16(a, b, acc[nt], 0, 0, 0);
    }
  }
}

// stage 64 rows x (4<<C4PR_LOG2) f32 cols from global into LDS bf16 [row][k] (pitch APK)
template<int C4PR_LOG2>
__device__ __forceinline__ void stage_rows(u16* a_s, const float* __restrict__ src,
                                           long n0, int t)
{
  const int c4pr = 1 << C4PR_LOG2;
  for (int idx = t; idx < 64*c4pr; idx += 256){
    int row = idx >> C4PR_LOG2, c4 = idx & (c4pr - 1);
    long n = n0 + row;
    float x0=0.f, x1=0.f, x2=0.f, x3=0.f;
    if (n < NN){
      const float4 v = *(const float4*)&src[(n << (C4PR_LOG2 + 2)) + c4*4];
      x0 = v.x; x1 = v.y; x2 = v.z; x3 = v.w;
    }
    usv4 o; o.x = f2b(x0); o.y = f2b(x1); o.z = f2b(x2); o.w = f2b(x3);
    *(usv4*)&a_s[row*APK + c4*4] = o;
  }
}

// ---------------- weight pre-pack into MFMA fragment order (bf16, K zero-padded to Ks<K) ---------
struct PD { const float* src; u16* dst; int K, N, Ks; };
struct PackArgs { PD d[8]; };

__global__ __launch_bounds__(64) void pack_weights(PackArgs A){
  int b = blockIdx.x, l = threadIdx.x;
  int mi = 0, base = 0;
  for (; mi < 8; mi++){
    int tiles = (A.d[mi].K >> 5) * (A.d[mi].N >> 4);
    if (b < base + tiles) break;
    base += tiles;
  }
  const PD d = A.d[mi];
  const int tile = b - base;
  const int ntn = d.N >> 4;
  const int ck = tile / ntn, nt = tile % ntn;
  const int lr = l & 15, q = l >> 4;
  const int col = nt*16 + lr;
  usv8 o;
  #pragma unroll
  for (int j = 0; j < 8; j++){
    int k = ck*32 + q*8 + j;
    o[j] = (k < d.Ks) ? f2b(d.src[(long)k * d.N + col]) : (u16)0;
  }
  *(usv8*)&d.dst[((long)tile*64 + l)*8] = o;
}

// ---------------- CSR build ----------------
__global__ __launch_bounds__(256) void csr_count(const int* __restrict__ recv,
    const int* __restrict__ send, int* cnt, int* pos_in, int* pos_out)
{
  int e = blockIdx.x*256 + threadIdx.x;
  if (e >= NE) return;
  pos_in [e] = atomicAdd(&cnt[recv[e]], 1);
  pos_out[e] = atomicAdd(&cnt[NN + send[e]], 1);
}

__global__ __launch_bounds__(256) void scan_blocks(const int* __restrict__ cnt,
    int* off, int* btot)
{
  __shared__ int s[256];
  int b = blockIdx.x, t = threadIdx.x;
  int i = b*256 + t;
  int v = (i < M2) ? cnt[i] : 0;
  s[t] = v; __syncthreads();
  int acc = v;
  for (int d = 1; d < 256; d <<= 1){
    int add = (t >= d) ? s[t-d] : 0;
    __syncthreads();
    acc += add; s[t] = acc;
    __syncthreads();
  }
  if (i < M2) off[i] = acc - v;     // block-local exclusive
  if (t == 255) btot[b] = acc;
}

__global__ __launch_bounds__(256) void scan_tops(int* btot){
  __shared__ int s[512], ts[256];
  int t = threadIdx.x;
  s[t]     = (t < SCAN_B) ? btot[t] : 0;
  s[256+t] = (256+t < SCAN_B) ? btot[256+t] : 0;
  __syncthreads();
  int a0 = s[2*t], a1 = s[2*t+1];
  int tot = a0 + a1;
  ts[t] = tot; __syncthreads();
  int acc = tot;
  for (int d = 1; d < 256; d <<= 1){
    int add = (t >= d) ? ts[t-d] : 0;
    __syncthreads();
    acc += add; ts[t] = acc;
    __syncthreads();
  }
  int excl = acc - tot;
  if (2*t   < SCAN_B) btot[2*t]   = excl;
  if (2*t+1 < SCAN_B) btot[2*t+1] = excl + a0;
}

__global__ __launch_bounds__(256) void scan_fix(int* off, const int* __restrict__ btot){
  int i = blockIdx.x*256 + threadIdx.x;
  if (i < M2) off[i] += btot[blockIdx.x];
}

__global__ __launch_bounds__(256) void csr_fill(const int* __restrict__ recv,
    const int* __restrict__ send, const int* __restrict__ off,
    const int* __restrict__ pos_in, const int* __restrict__ pos_out, int* lis)
{
  int e = blockIdx.x*256 + threadIdx.x;
  if (e >= NE) return;
  lis[off[recv[e]]      + pos_in [e]] = e;
  lis[off[NN + send[e]] + pos_out[e]] = e;
}

// ---------------- edge block 1: e1 = relu(edges@We1+be1) via MFMA, rows -> e1b (bf16) ------------
__global__ __launch_bounds__(256) void edge1_kernel(const float* __restrict__ edges,
    const u16* __restrict__ pWe1, const float* __restrict__ be1,
    u16* __restrict__ e1b, float* __restrict__ e1_cs)
{
  __shared__ __align__(16) u16 a_es[64*EP1];
  __shared__ float cs_s[H1];
  const int t = threadIdx.x;
  const long e0 = (long)blockIdx.x * 64;
  const int w = t >> 6, l = t & 63, lr = l & 15, q = l >> 4;
  cs_s[t] = 0.f;
  {
    int row = t >> 2, c4 = t & 3;
    float4 v = *(const float4*)&edges[(e0 + row)*FE + c4*4];
    usv4 o = { f2b(v.x), f2b(v.y), f2b(v.z), f2b(v.w) };
    *(usv4*)&a_es[row*EP1 + c4*4] = o;
    *(usv4*)&a_es[row*EP1 + 16 + c4*4] = (usv4){0,0,0,0};   // zero-pad k=16..31
  }
  __syncthreads();
  f32v4 acc[16];
  #pragma unroll
  for (int nt = 0; nt < 16; nt++) acc[nt] = (f32v4){0.f,0.f,0.f,0.f};
  gemm_tiles<1,16,EP1>(a_es, pWe1, w, l, acc);

  #pragma unroll
  for (int nt = 0; nt < 16; nt++){
    const int j = nt*16 + lr;
    const float b = be1[j];
    float part = 0.f;
    #pragma unroll
    for (int r = 0; r < 4; r++){
      const int m = w*16 + q*4 + r;
      float v = fmaxf(acc[nt][r] + b, 0.f);
      e1b[(e0 + m)*H1 + j] = f2b(v);
      part += v;
    }
    atomicAdd(&cs_s[j], part);
  }
  __syncthreads();
  atomicAdd(&e1_cs[t], cs_s[t]);
}

// ---------------- edge block 2: in-place e1b (bf16 rows) -> e2 (f32 rows) -----------------------
__global__ __launch_bounds__(256) void e2_kernel(float* __restrict__ e2f,
    const u16* __restrict__ pWe2, const float* __restrict__ be2, float* __restrict__ e2_cs)
{
  __shared__ __align__(16) u16 a_s[64*APK];
  __shared__ float cs_s[H2];
  const int t = threadIdx.x;
  const long e0 = (long)blockIdx.x * 64;
  const int w = t >> 6, l = t & 63, lr = l & 15, q = l >> 4;
  if (t < H2) cs_s[t] = 0.f;
  const u16* e1u = (const u16*)e2f;
  for (int idx = t; idx < 64*32; idx += 256){
    int row = idx >> 5, ch = idx & 31;
    usv8 v = *(const usv8*)&e1u[(e0 + row)*H1 + ch*8];
    *(usv8*)&a_s[row*APK + ch*8] = v;
  }
  __syncthreads();   // all reads of this block's rows complete before overwrite below
  f32v4 acc[8];
  #pragma unroll
  for (int nt = 0; nt < 8; nt++) acc[nt] = (f32v4){0.f,0.f,0.f,0.f};
  gemm_tiles<8,8,APK>(a_s, pWe2, w, l, acc);

  #pragma unroll
  for (int nt = 0; nt < 8; nt++){
    const int j = nt*16 + lr;
    const float b = be2[j];
    float part = 0.f;
    #pragma unroll
    for (int r = 0; r < 4; r++){
      const int m = w*16 + q*4 + r;
      float v = fmaxf(acc[nt][r] + b, 0.f);
      e2f[(e0 + m)*H2 + j] = v;
      part += v;
    }
    atomicAdd(&cs_s[j], part);
  }
  __syncthreads();
  if (t < H2) atomicAdd(&e2_cs[t], cs_s[t]);
}

// ---------------- gathers: mean of rows listed in CSR -> LDS A-tile ----------------
// Depth-4 pipelined: 4 independent row loads in flight before each accumulate, so the
// compiler issues 4 global_loads per waitcnt instead of serializing a dependent chain.
// Fast path (re<=LCAP, block-uniform in practice) removes the per-element LCAP predicate.
template<int PITCH>
__device__ __forceinline__ void gather_h1(u16* a_s, const u16* __restrict__ src,
    const int* lst, const int* roff, int base, const int* __restrict__ lis_g, int w, int l)
{
  for (int rr = 0; rr < 16; rr++){
    int r = w + rr*4;
    int rs = roff[r] - base, re = roff[r+1] - base;
    float s0=0.f, s1=0.f, s2=0.f, s3=0.f;
    int j = rs;
    if (re <= LCAP){
      for (; j + 4 <= re; j += 4){
        int eA = lst[j], eB = lst[j+1], eC = lst[j+2], eD = lst[j+3];
        usv4 a = *(const usv4*)&src[(long)eA*H1 + l*4];
        usv4 b = *(const usv4*)&src[(long)eB*H1 + l*4];
        usv4 c = *(const usv4*)&src[(long)eC*H1 + l*4];
        usv4 d = *(const usv4*)&src[(long)eD*H1 + l*4];
        s0 += (bf2f(a.x)+bf2f(b.x)) + (bf2f(c.x)+bf2f(d.x));
        s1 += (bf2f(a.y)+bf2f(b.y)) + (bf2f(c.y)+bf2f(d.y));
        s2 += (bf2f(a.z)+bf2f(b.z)) + (bf2f(c.z)+bf2f(d.z));
        s3 += (bf2f(a.w)+bf2f(b.w)) + (bf2f(c.w)+bf2f(d.w));
      }
      if (j + 2 <= re){
        int eA = lst[j], eB = lst[j+1]; j += 2;
        usv4 a = *(const usv4*)&src[(long)eA*H1 + l*4];
        usv4 b = *(const usv4*)&src[(long)eB*H1 + l*4];
        s0 += bf2f(a.x)+bf2f(b.x); s1 += bf2f(a.y)+bf2f(b.y);
        s2 += bf2f(a.z)+bf2f(b.z); s3 += bf2f(a.w)+bf2f(b.w);
      }
      if (j < re){
        int eA = lst[j];
        usv4 a = *(const usv4*)&src[(long)eA*H1 + l*4];
        s0 += bf2f(a.x); s1 += bf2f(a.y); s2 += bf2f(a.z); s3 += bf2f(a.w);
      }
    } else {
      for (; j < re; ++j){
        int eA = (j < LCAP) ? lst[j] : lis_g[base + j];
        usv4 a = *(const usv4*)&src[(long)eA*H1 + l*4];
        s0 += bf2f(a.x); s1 += bf2f(a.y); s2 += bf2f(a.z); s3 += bf2f(a.w);
      }
    }
    float rd = 1.f / fmaxf((float)(re - rs), 1.f);
    usv4 o = { f2b(s0*rd), f2b(s1*rd), f2b(s2*rd), f2b(s3*rd) };
    *(usv4*)&a_s[r*PITCH + l*4] = o;
  }
}

template<int PITCH>
__device__ __forceinline__ void gather_h2(u16* a_s, const float* __restrict__ src,
    const int* lst, const int* roff, int base, const int* __restrict__ lis_g, int w, int l)
{
  for (int rr = 0; rr < 16; rr++){
    int r = w + rr*4;
    int rs = roff[r] - base, re = roff[r+1] - base;
    float s0=0.f, s1=0.f;
    int j = rs;
    if (re <= LCAP){
      for (; j + 4 <= re; j += 4){
        int eA = lst[j], eB = lst[j+1], eC = lst[j+2], eD = lst[j+3];
        float2 a = *(const float2*)&src[(long)eA*H2 + l*2];
        float2 b = *(const float2*)&src[(long)eB*H2 + l*2];
        float2 c = *(const float2*)&src[(long)eC*H2 + l*2];
        float2 d = *(const float2*)&src[(long)eD*H2 + l*2];
        s0 += (a.x+b.x) + (c.x+d.x);
        s1 += (a.y+b.y) + (c.y+d.y);
      }
      if (j + 2 <= re){
        int eA = lst[j], eB = lst[j+1]; j += 2;
        float2 a = *(const float2*)&src[(long)eA*H2 + l*2];
        float2 b = *(const float2*)&src[(long)eB*H2 + l*2];
        s0 += a.x + b.x; s1 += a.y + b.y;
      }
      if (j < re){
        int eA = lst[j];
        float2 a = *(const float2*)&src[(long)eA*H2 + l*2];
        s0 += a.x; s1 += a.y;
      }
    } else {
      for (; j < re; ++j){
        int eA = (j < LCAP) ? lst[j] : lis_g[base + j];
        float2 a = *(const float2*)&src[(long)eA*H2 + l*2];
        s0 += a.x; s1 += a.y;
      }
    }
    float rd = 1.f / fmaxf((float)(re - rs), 1.f);
    usv2 o = { f2b(s0*rd), f2b(s1*rd) };
    *(usv2*)&a_s[r*PITCH + l*2] = o;
  }
}

// ---------------- node block 1 ----------------
// __launch_bounds__(256,3): cap VGPR<=168 so 3 blocks/CU fit (LDS allows 3; 180 VGPR allowed only 2)
__global__ __launch_bounds__(256, 3) void node1_kernel(
    const float* __restrict__ nodes, const u16* __restrict__ e1b,
    const int* __restrict__ off, const int* __restrict__ lis,
    const u16* __restrict__ pWn1, const u16* __restrict__ pWin1, const u16* __restrict__ pWout1,
    const float* __restrict__ bn1, u16* __restrict__ n1b, float* __restrict__ n1_cs)
{
  __shared__ __align__(16) u16 a_s[64*APK];
  __shared__ int ilA[LCAP], ilB[LCAP];
  __shared__ int roff[65], roff2[65];
  __shared__ float cs_s[H1];
  const int t = threadIdx.x;
  const long n0 = (long)blockIdx.x * 64;
  const int w = t >> 6, l = t & 63, lr = l & 15, q = l >> 4;

  cs_s[t] = 0.f;
  if (t <= 64){
    long idx = n0 + t;
    roff [t] = (idx >= NN) ? NE     : off[idx];
    roff2[t] = (idx >= NN) ? 2*NE   : off[NN + idx];
  }
  __syncthreads();
  const int inb = roff[0],  in_total  = roff[64]  - inb;
  const int onb = roff2[0], out_total = roff2[64] - onb;
  for (int j = t; j < in_total  && j < LCAP; j += 256) ilA[j] = lis[inb + j];
  for (int j = t; j < out_total && j < LCAP; j += 256) ilB[j] = lis[onb + j];
  __syncthreads();

  f32v4 acc[16];
  #pragma unroll
  for (int nt = 0; nt < 16; nt++) acc[nt] = (f32v4){0.f,0.f,0.f,0.f};

  gather_h1<APK>(a_s, e1b, ilA, roff, inb, lis, w, l);
  __syncthreads();
  gemm_tiles<8,16,APK>(a_s, pWin1, w, l, acc);
  __syncthreads();

  gather_h1<APK>(a_s, e1b, ilB, roff2, onb, lis, w, l);
  __syncthreads();
  gemm_tiles<8,16,APK>(a_s, pWout1, w, l, acc);
  __syncthreads();

  stage_rows<3>(a_s, nodes, n0, t);
  __syncthreads();
  gemm_tiles<1,16,APK>(a_s, pWn1, w, l, acc);

  #pragma unroll
  for (int nt = 0; nt < 16; nt++){
    const int j = nt*16 + lr;
    const float b = bn1[j];
    float part = 0.f;
    #pragma unroll
    for (int r = 0; r < 4; r++){
      const int row = w*16 + q*4 + r;
      const long n = n0 + row;
      if (n < NN){
        float v = fmaxf(acc[nt][r] + b, 0.f);
        n1b[n*H1 + j] = f2b(v);
        part += v;
      }
    }
    atomicAdd(&cs_s[j], part);
  }
  __syncthreads();
  atomicAdd(&n1_cs[t], cs_s[t]);
}

// ---------------- node block 2 ----------------
// __launch_bounds__(256,4): cap VGPR<=128 -> 4 blocks/CU. LDS shrunk to 64xAP2 (K=128 tiles);
// the n1 @ Wn2 GEMM (K=256) is done in two K=128 staged halves.
__global__ __launch_bounds__(256, 4) void node2_kernel(
    const u16* __restrict__ n1b, const float* __restrict__ e2f,
    const int* __restrict__ off, const int* __restrict__ lis,
    const u16* __restrict__ pWn2, const u16* __restrict__ pWin2, const u16* __restrict__ pWout2,
    const float* __restrict__ bn2, float* __restrict__ n2_out, float* __restrict__ n2_cs)
{
  __shared__ __align__(16) u16 a_s[64*AP2];
  __shared__ int ilA[LCAP], ilB[LCAP];
  __shared__ int roff[65], roff2[65];
  __shared__ float cs_s[H2];
  const int t = threadIdx.x;
  const long n0 = (long)blockIdx.x * 64;
  const int w = t >> 6, l = t & 63, lr = l & 15, q = l >> 4;

  if (t < H2) cs_s[t] = 0.f;
  if (t <= 64){
    long idx = n0 + t;
    roff [t] = (idx >= NN) ? NE     : off[idx];
    roff2[t] = (idx >= NN) ? 2*NE   : off[NN + idx];
  }
  __syncthreads();
  const int inb = roff[0],  in_total  = roff[64]  - inb;
  const int onb = roff2[0], out_total = roff2[64] - onb;
  for (int j = t; j < in_total  && j < LCAP; j += 256) ilA[j] = lis[inb + j];
  for (int j = t; j < out_total && j < LCAP; j += 256) ilB[j] = lis[onb + j];
  __syncthreads();

  f32v4 acc[8];
  #pragma unroll
  for (int nt = 0; nt < 8; nt++) acc[nt] = (f32v4){0.f,0.f,0.f,0.f};

  // A = n1 (bf16 rows), K=256 processed as two K=128 half-tiles
  for (int h = 0; h < 2; h++){
    for (int idx = t; idx < 64*16; idx += 256){
      int row = idx >> 4, ch = idx & 15;
      long n = n0 + row;
      usv8 v = (usv8){0,0,0,0,0,0,0,0};
      if (n < NN) v = *(const usv8*)&n1b[n*H1 + h*128 + ch*8];
      *(usv8*)&a_s[row*AP2 + ch*8] = v;
    }
    __syncthreads();
    gemm_tiles<4,8,AP2>(a_s, pWn2 + h*(4*8*64*8), w, l, acc);
    __syncthreads();
  }

  gather_h2<AP2>(a_s, e2f, ilA, roff, inb, lis, w, l);
  __syncthreads();
  gemm_tiles<4,8,AP2>(a_s, pWin2, w, l, acc);
  __syncthreads();

  gather_h2<AP2>(a_s, e2f, ilB, roff2, onb, lis, w, l);
  __syncthreads();
  gemm_tiles<4,8,AP2>(a_s, pWout2, w, l, acc);

  #pragma unroll
  for (int nt = 0; nt < 8; nt++){
    const int j = nt*16 + lr;
    const float b = bn2[j];
    float part = 0.f;
    #pragma unroll
    for (int r = 0; r < 4; r++){
      const int row = w*16 + q*4 + r;
      const long n = n0 + row;
      if (n < NN){
        float v = fmaxf(acc[nt][r] + b, 0.f);
        n2_out[n*H2 + j] = v;
        part += v;
      }
    }
    atomicAdd(&cs_s[j], part);
  }
  __syncthreads();
  if (t < H2) atomicAdd(&n2_cs[t], cs_s[t]);
}

// ---------------- global updates ----------------
__global__ void u1_kernel(const float* __restrict__ gu, const float* __restrict__ Wu1,
    const float* __restrict__ Wgn1, const float* __restrict__ Wge1, const float* __restrict__ bu1,
    const float* __restrict__ n1_cs, const float* __restrict__ e1_cs, float* __restrict__ u1v)
{
    const int j = threadIdx.x;
    float acc = bu1[j];
    #pragma unroll
    for (int k = 0; k < FG; k++) acc += gu[k] * Wu1[k*H1 + j];
    for (int k = 0; k < H1; k++) acc += (n1_cs[k] * (1.f/NN)) * Wgn1[k*H1 + j];
    for (int k = 0; k < H1; k++) acc += (e1_cs[k] * (1.f/NE)) * Wge1[k*H1 + j];
    u1v[j] = fmaxf(acc, 0.f);
}

__global__ void u2_kernel(const float* __restrict__ u1v, const float* __restrict__ Wu2,
    const float* __restrict__ Wgn2, const float* __restrict__ Wge2, const float* __restrict__ bu2,
    const float* __restrict__ n2_cs, const float* __restrict__ e2_cs, float* __restrict__ u2_out)
{
    const int j = threadIdx.x;
    float acc = bu2[j];
    for (int k = 0; k < H1; k++) acc += u1v[k] * Wu2[k*H2 + j];
    for (int k = 0; k < H2; k++) acc += (n2_cs[k] * (1.f/NN)) * Wgn2[k*H2 + j];
    for (int k = 0; k < H2; k++) acc += (e2_cs[k] * (1.f/NE)) * Wge2[k*H2 + j];
    u2_out[j] = fmaxf(acc, 0.f);
}

// ---------------- launcher ----------------
extern "C" void kernel_launch(void* const* d_in, const int* in_sizes, int n_in,
                              void* d_out, int out_size, void* d_ws, size_t ws_size,
                              hipStream_t stream)
{
    (void)in_sizes; (void)n_in; (void)out_size; (void)ws_size;
    const float* nodes = (const float*)d_in[0];
    const float* edges = (const float*)d_in[1];
    const float* gu    = (const float*)d_in[2];
    const int* senders   = (const int*)d_in[3];
    const int* receivers = (const int*)d_in[4];
    const float* We1  = (const float*)d_in[5];  const float* be1 = (const float*)d_in[6];
    const float* Wn1  = (const float*)d_in[7];  const float* Win1= (const float*)d_in[8];
    const float* Wout1= (const float*)d_in[9];  const float* bn1 = (const float*)d_in[10];
    const float* Wu1  = (const float*)d_in[11]; const float* Wgn1= (const float*)d_in[12];
    const float* Wge1 = (const float*)d_in[13]; const float* bu1 = (const float*)d_in[14];
    const float* We2  = (const float*)d_in[15]; const float* be2 = (const float*)d_in[16];
    const float* Wn2  = (const float*)d_in[17]; const float* Win2= (const float*)d_in[18];
    const float* Wout2= (const float*)d_in[19]; const float* bn2 = (const float*)d_in[20];
    const float* Wu2  = (const float*)d_in[21]; const float* Wgn2= (const float*)d_in[22];
    const float* Wge2 = (const float*)d_in[23]; const float* bu2 = (const float*)d_in[24];

    float* ws = (float*)d_ws;
    size_t o = 0;
    int*   cnt    = (int*)(ws + o);  o += M2;        // zeroed
    float* e1_cs  = ws + o;          o += 256;       // zeroed
    float* n1_cs  = ws + o;          o += 256;       // zeroed
    float* e2_cs  = ws + o;          o += 128;       // zeroed
    float* n2_cs  = ws + o;          o += 128;       // zeroed
    const size_t zero_bytes = o * sizeof(float);
    float* u1v    = ws + o;          o += 256;
    int*   off    = (int*)(ws + o);  o += M2;
    int*   pos_in = (int*)(ws + o);  o += NE;
    int*   pos_out= (int*)(ws + o);  o += NE;
    int*   lis    = (int*)(ws + o);  o += 2*NE;
    int*   btot   = (int*)(ws + o);  o += 400;

    u16* pbase = (u16*)(ws + o);
    size_t po = 0;
    u16* pWin1 = pbase + po;  po += (size_t)H1*H1;
    u16* pWout1= pbase + po;  po += (size_t)H1*H1;
    u16* pWn1  = pbase + po;  po += (size_t)FN*H1;
    u16* pWe1  = pbase + po;  po += (size_t)32*H1;   // K padded 16->32
    u16* pWe2  = pbase + po;  po += (size_t)H1*H2;
    u16* pWn2  = pbase + po;  po += (size_t)H1*H2;
    u16* pWin2 = pbase + po;  po += (size_t)H2*H2;
    u16* pWout2= pbase + po;  po += (size_t)H2*H2;
    o += (po + 1) / 2;

    u16* n1b = (u16*)(ws + o);       // NN*H1 bf16 = 25.6 MB

    float* n2_out = (float*)d_out;
    float* e2f    = n2_out + (size_t)NN*H2;          // e2 region; also scratch for e1 (bf16)
    float* u2_out = n2_out + (size_t)(NN + NE)*H2;
    u16*   e1b    = (u16*)e2f;                       // e1 bf16 rows live here until e2_kernel

    hipMemsetAsync(d_ws, 0, zero_bytes, stream);

    PackArgs pa;
    pa.d[0] = {Win1,  pWin1,  H1, H1, H1};
    pa.d[1] = {Wout1, pWout1, H1, H1, H1};
    pa.d[2] = {Wn1,   pWn1,   FN, H1, FN};
    pa.d[3] = {We1,   pWe1,   32, H1, FE};
    pa.d[4] = {We2,   pWe2,   H1, H2, H1};
    pa.d[5] = {Wn2,   pWn2,   H1, H2, H1};
    pa.d[6] = {Win2,  pWin2,  H2, H2, H2};
    pa.d[7] = {Wout2, pWout2, H2, H2, H2};
    int total_tiles = 0;
    for (int i = 0; i < 8; i++) total_tiles += (pa.d[i].K >> 5) * (pa.d[i].N >> 4);
    pack_weights<<<total_tiles, 64, 0, stream>>>(pa);

    const int EG = (NE + 255)/256;
    csr_count<<<EG, 256, 0, stream>>>(receivers, senders, cnt, pos_in, pos_out);
    scan_blocks<<<SCAN_B, 256, 0, stream>>>(cnt, off, btot);
    scan_tops<<<1, 256, 0, stream>>>(btot);
    scan_fix<<<SCAN_B, 256, 0, stream>>>(off, btot);
    csr_fill<<<EG, 256, 0, stream>>>(receivers, senders, off, pos_in, pos_out, lis);

    edge1_kernel<<<NE/64, 256, 0, stream>>>(edges, pWe1, be1, e1b, e1_cs);

    node1_kernel<<<(NN + 63)/64, 256, 0, stream>>>(nodes, e1b, off, lis,
        pWn1, pWin1, pWout1, bn1, n1b, n1_cs);

    u1_kernel<<<1, H1, 0, stream>>>(gu, Wu1, Wgn1, Wge1, bu1, n1_cs, e1_cs, u1v);

    e2_kernel<<<NE/64, 256, 0, stream>>>(e2f, pWe2, be2, e2_cs);

    node2_kernel<<<(NN + 63)/64, 256, 0, stream>>>(n1b, e2f, off, lis,
        pWn2, pWin2, pWout2, bn2, n2_out, n2_cs);

    u2_kernel<<<1, H2, 0, stream>>>(u1v, Wu2, Wgn2, Wge2, bu2, n2_cs, e2_cs, u2_out);
}

// Round 3
// 1012.140 us; speedup vs baseline: 1.2243x; 1.0316x over previous
//
#include <hip/hip_runtime.h>
#include <hip/hip_bf16.h>
#include <stdint.h>

#define NN 50000
#define NE 400000
#define FN 32
#define FE 16
#define FG 16
#define H1 256
#define H2 128
#define M2 (2*NN)          // concatenated [in-counts, out-counts]
#define SCAN_B 391         // ceil(M2/256)
#define LCAP 1536          // staged edge-list capacity per tile per direction
#define NPART 256          // partial-sum copies for column sums (atomic spreading)

typedef unsigned short u16;
typedef __bf16 bfv8 __attribute__((ext_vector_type(8)));
typedef float f32v4 __attribute__((ext_vector_type(4)));
typedef u16 usv2 __attribute__((ext_vector_type(2)));
typedef u16 usv4 __attribute__((ext_vector_type(4)));
typedef u16 usv8 __attribute__((ext_vector_type(8)));

#define APK 264   // LDS pitch (bf16 elems): 528B rows (node1/e2: K=256 tiles)
#define AP2 136   // LDS pitch for node2's K=128 tiles
#define EP1 40    // LDS pitch for edge1's 64x32 tile

// Column-permuted storage for e1b / n1b (both workspace-only):
//   stored col c' = lr*16 + nt holds original col j = nt*16 + lr  (nibble swap, involution)
//   g1(c) = ((c&15)<<4) | (c>>4)
// Consumers whose A-tile preserves that permuted order pack weights with perm=1 (K-rows by g1).
// gather_h2 writes CANONICAL order (reads canonical e2f) -> Win2/Wout2 pack with perm=0.
// e2f stays canonical (harness output) -> swizzled-LDS transpose for vector stores.

__device__ __forceinline__ u16 f2b(float x){
  __hip_bfloat16 h = __float2bfloat16(x);
  return *reinterpret_cast<u16*>(&h);
}
__device__ __forceinline__ float bf2f(u16 u){
  union{uint32_t i; float f;} v; v.i = ((uint32_t)u) << 16; return v.f;
}

// ---------------- MFMA GEMM over LDS A-tile [row][k] and frag-packed B ----------------
template<int NCK, int NNT, int PITCH>
__device__ __forceinline__ void gemm_tiles(const u16* a_s, const u16* __restrict__ pB,
                                           int w, int l, f32v4* acc)
{
  const int lr = l & 15, q = l >> 4;
  const bfv8* bp = (const bfv8*)pB;
  for (int ck = 0; ck < NCK; ck++){
    bfv8 a = *(const bfv8*)&a_s[(w*16 + lr)*PITCH + ck*32 + q*8];
    #pragma unroll
    for (int nt = 0; nt < NNT; nt++){
      bfv8 b = bp[(ck*NNT + nt)*64 + l];
      acc[nt] = __builtin_amdgcn_mfma_f32_16x16x32_bf16(a, b, acc[nt], 0, 0, 0);
    }
  }
}

// stage 64 rows x (4<<C4PR_LOG2) f32 cols from global into LDS bf16 [row][k] (pitch APK)
template<int C4PR_LOG2>
__device__ __forceinline__ void stage_rows(u16* a_s, const float* __restrict__ src,
                                           long n0, int t)
{
  const int c4pr = 1 << C4PR_LOG2;
  for (int idx = t; idx < 64*c4pr; idx += 256){
    int row = idx >> C4PR_LOG2, c4 = idx & (c4pr - 1);
    long n = n0 + row;
    float x0=0.f, x1=0.f, x2=0.f, x3=0.f;
    if (n < NN){
      const float4 v = *(const float4*)&src[(n << (C4PR_LOG2 + 2)) + c4*4];
      x0 = v.x; x1 = v.y; x2 = v.z; x3 = v.w;
    }
    usv4 o; o.x = f2b(x0); o.y = f2b(x1); o.z = f2b(x2); o.w = f2b(x3);
    *(usv4*)&a_s[row*APK + c4*4] = o;
  }
}

// ---------------- weight pre-pack into MFMA fragment order ----------------
// perm: 0 = none, 1 = g1 (256-wide nibble swap on K index)
struct PD { const float* src; u16* dst; int K, N, Ks, perm; };
struct PackArgs { PD d[8]; };

__global__ __launch_bounds__(64) void pack_weights(PackArgs A){
  int b = blockIdx.x, l = threadIdx.x;
  int mi = 0, base = 0;
  for (; mi < 8; mi++){
    int tiles = (A.d[mi].K >> 5) * (A.d[mi].N >> 4);
    if (b < base + tiles) break;
    base += tiles;
  }
  const PD d = A.d[mi];
  const int tile = b - base;
  const int ntn = d.N >> 4;
  const int ck = tile / ntn, nt = tile % ntn;
  const int lr = l & 15, q = l >> 4;
  const int col = nt*16 + lr;
  usv8 o;
  #pragma unroll
  for (int j = 0; j < 8; j++){
    int k = ck*32 + q*8 + j;
    int sk = (d.perm == 1) ? (((k & 15) << 4) | (k >> 4)) : k;
    o[j] = (k < d.Ks) ? f2b(d.src[(long)sk * d.N + col]) : (u16)0;
  }
  *(usv8*)&d.dst[((long)tile*64 + l)*8] = o;
}

// ---------------- CSR build ----------------
__global__ __launch_bounds__(256) void csr_count(const int* __restrict__ recv,
    const int* __restrict__ send, int* cnt, int* pos_in, int* pos_out)
{
  int e = blockIdx.x*256 + threadIdx.x;
  if (e >= NE) return;
  pos_in [e] = atomicAdd(&cnt[recv[e]], 1);
  pos_out[e] = atomicAdd(&cnt[NN + send[e]], 1);
}

__global__ __launch_bounds__(256) void scan_blocks(const int* __restrict__ cnt,
    int* off, int* btot)
{
  __shared__ int s[256];
  int b = blockIdx.x, t = threadIdx.x;
  int i = b*256 + t;
  int v = (i < M2) ? cnt[i] : 0;
  s[t] = v; __syncthreads();
  int acc = v;
  for (int d = 1; d < 256; d <<= 1){
    int add = (t >= d) ? s[t-d] : 0;
    __syncthreads();
    acc += add; s[t] = acc;
    __syncthreads();
  }
  if (i < M2) off[i] = acc - v;     // block-local exclusive
  if (t == 255) btot[b] = acc;
}

__global__ __launch_bounds__(256) void scan_tops(int* btot){
  __shared__ int s[512], ts[256];
  int t = threadIdx.x;
  s[t]     = (t < SCAN_B) ? btot[t] : 0;
  s[256+t] = (256+t < SCAN_B) ? btot[256+t] : 0;
  __syncthreads();
  int a0 = s[2*t], a1 = s[2*t+1];
  int tot = a0 + a1;
  ts[t] = tot; __syncthreads();
  int acc = tot;
  for (int d = 1; d < 256; d <<= 1){
    int add = (t >= d) ? ts[t-d] : 0;
    __syncthreads();
    acc += add; ts[t] = acc;
    __syncthreads();
  }
  int excl = acc - tot;
  if (2*t   < SCAN_B) btot[2*t]   = excl;
  if (2*t+1 < SCAN_B) btot[2*t+1] = excl + a0;
}

__global__ __launch_bounds__(256) void scan_fix(int* off, const int* __restrict__ btot){
  int i = blockIdx.x*256 + threadIdx.x;
  if (i < M2) off[i] += btot[blockIdx.x];
}

__global__ __launch_bounds__(256) void csr_fill(const int* __restrict__ recv,
    const int* __restrict__ send, const int* __restrict__ off,
    const int* __restrict__ pos_in, const int* __restrict__ pos_out, int* lis)
{
  int e = blockIdx.x*256 + threadIdx.x;
  if (e >= NE) return;
  lis[off[recv[e]]      + pos_in [e]] = e;
  lis[off[NN + send[e]] + pos_out[e]] = e;
}

// ---------------- edge block 1: e1 = relu(edges@We1+be1), permuted cols -> e1b (bf16) ------------
__global__ __launch_bounds__(256) void edge1_kernel(const float* __restrict__ edges,
    const u16* __restrict__ pWe1, const float* __restrict__ be1,
    u16* __restrict__ e1b, float* __restrict__ e1p)
{
  __shared__ __align__(16) u16 a_es[64*EP1];
  __shared__ float cs_s[H1];
  __shared__ float bs[H1];
  const int t = threadIdx.x;
  const long e0 = (long)blockIdx.x * 64;
  const int w = t >> 6, l = t & 63, lr = l & 15, q = l >> 4;
  cs_s[t] = 0.f;
  bs[t] = be1[t];
  {
    int row = t >> 2, c4 = t & 3;
    float4 v = *(const float4*)&edges[(e0 + row)*FE + c4*4];
    usv4 o = { f2b(v.x), f2b(v.y), f2b(v.z), f2b(v.w) };
    *(usv4*)&a_es[row*EP1 + c4*4] = o;
    *(usv4*)&a_es[row*EP1 + 16 + c4*4] = (usv4){0,0,0,0};   // zero-pad k=16..31
  }
  __syncthreads();
  f32v4 acc[16];
  #pragma unroll
  for (int nt = 0; nt < 16; nt++) acc[nt] = (f32v4){0.f,0.f,0.f,0.f};
  gemm_tiles<1,16,EP1>(a_es, pWe1, w, l, acc);

  // bias+relu in place; column sums in ORIGINAL col order
  #pragma unroll
  for (int nt = 0; nt < 16; nt++){
    const float b = bs[nt*16 + lr];
    float part = 0.f;
    #pragma unroll
    for (int r = 0; r < 4; r++){
      float v = fmaxf(acc[nt][r] + b, 0.f);
      acc[nt][r] = v; part += v;
    }
    atomicAdd(&cs_s[nt*16 + lr], part);
  }
  // vectorized stores: stored col' = lr*16 + nt -> 2x usv8 (16B) per row
  #pragma unroll
  for (int r = 0; r < 4; r++){
    const int m = w*16 + q*4 + r;
    usv8 o0, o1;
    #pragma unroll
    for (int h = 0; h < 8; h++){ o0[h] = f2b(acc[h][r]); o1[h] = f2b(acc[8+h][r]); }
    *(usv8*)&e1b[(e0 + m)*H1 + lr*16]     = o0;
    *(usv8*)&e1b[(e0 + m)*H1 + lr*16 + 8] = o1;
  }
  __syncthreads();
  atomicAdd(&e1p[(blockIdx.x & (NPART-1))*H1 + t], cs_s[t]);
}

// ---------------- edge block 2: in-place e1b (perm bf16 rows) -> e2 (canonical f32 rows) --------
__global__ __launch_bounds__(256) void e2_kernel(float* __restrict__ e2f,
    const u16* __restrict__ pWe2, const float* __restrict__ be2, float* __restrict__ e2p)
{
  __shared__ __align__(16) u16 a_s[64*APK];   // 33792B; aliased below as f32 out-tile (32768B)
  __shared__ float cs_s[H2];
  __shared__ float bs[H2];
  const int t = threadIdx.x;
  const long e0 = (long)blockIdx.x * 64;
  const int w = t >> 6, l = t & 63, lr = l & 15, q = l >> 4;
  if (t < H2){ cs_s[t] = 0.f; bs[t] = be2[t]; }
  const u16* e1u = (const u16*)e2f;
  for (int idx = t; idx < 64*32; idx += 256){
    int row = idx >> 5, ch = idx & 31;
    usv8 v = *(const usv8*)&e1u[(e0 + row)*H1 + ch*8];
    *(usv8*)&a_s[row*APK + ch*8] = v;
  }
  __syncthreads();
  f32v4 acc[8];
  #pragma unroll
  for (int nt = 0; nt < 8; nt++) acc[nt] = (f32v4){0.f,0.f,0.f,0.f};
  gemm_tiles<8,8,APK>(a_s, pWe2, w, l, acc);

  #pragma unroll
  for (int nt = 0; nt < 8; nt++){
    const float b = bs[nt*16 + lr];
    float part = 0.f;
    #pragma unroll
    for (int r = 0; r < 4; r++){
      float v = fmaxf(acc[nt][r] + b, 0.f);
      acc[nt][r] = v; part += v;
    }
    atomicAdd(&cs_s[nt*16 + lr], part);
  }
  __syncthreads();                 // all GEMM reads of a_s complete
  // canonical-layout output via XOR-swizzled LDS transpose (2-way conflicts only)
  float* fl = (float*)a_s;
  #pragma unroll
  for (int r = 0; r < 4; r++){
    const int m = w*16 + q*4 + r;
    const int sw = (m & 7) * 4;
    #pragma unroll
    for (int nt = 0; nt < 8; nt++)
      fl[m*128 + ((nt*16 + lr) ^ sw)] = acc[nt][r];
  }
  __syncthreads();
  {
    const int row = t >> 2, c = t & 3;
    const int sw = (row & 7) * 4;
    #pragma unroll
    for (int k = 0; k < 8; k++){
      const int wi = (c*32 + k*4) ^ sw;
      float4 v = *(const float4*)&fl[row*128 + wi];
      *(float4*)&e2f[(e0 + row)*H2 + c*32 + k*4] = v;
    }
  }
  if (t < H2) atomicAdd(&e2p[(blockIdx.x & (NPART-1))*H2 + t], cs_s[t]);
}

// ---------------- gathers: mean of rows listed in CSR -> LDS A-tile ----------------
template<int PITCH>
__device__ __forceinline__ void gather_h1(u16* a_s, const u16* __restrict__ src,
    const int* lst, const int* roff, int base, const int* __restrict__ lis_g, int w, int l)
{
  for (int rr = 0; rr < 16; rr++){
    int r = w + rr*4;
    int rs = roff[r] - base, re = roff[r+1] - base;
    float s0=0.f, s1=0.f, s2=0.f, s3=0.f;
    int j = rs;
    if (re <= LCAP){
      for (; j + 4 <= re; j += 4){
        int eA = lst[j], eB = lst[j+1], eC = lst[j+2], eD = lst[j+3];
        usv4 a = *(const usv4*)&src[(long)eA*H1 + l*4];
        usv4 b = *(const usv4*)&src[(long)eB*H1 + l*4];
        usv4 c = *(const usv4*)&src[(long)eC*H1 + l*4];
        usv4 d = *(const usv4*)&src[(long)eD*H1 + l*4];
        s0 += (bf2f(a.x)+bf2f(b.x)) + (bf2f(c.x)+bf2f(d.x));
        s1 += (bf2f(a.y)+bf2f(b.y)) + (bf2f(c.y)+bf2f(d.y));
        s2 += (bf2f(a.z)+bf2f(b.z)) + (bf2f(c.z)+bf2f(d.z));
        s3 += (bf2f(a.w)+bf2f(b.w)) + (bf2f(c.w)+bf2f(d.w));
      }
      if (j + 2 <= re){
        int eA = lst[j], eB = lst[j+1]; j += 2;
        usv4 a = *(const usv4*)&src[(long)eA*H1 + l*4];
        usv4 b = *(const usv4*)&src[(long)eB*H1 + l*4];
        s0 += bf2f(a.x)+bf2f(b.x); s1 += bf2f(a.y)+bf2f(b.y);
        s2 += bf2f(a.z)+bf2f(b.z); s3 += bf2f(a.w)+bf2f(b.w);
      }
      if (j < re){
        int eA = lst[j];
        usv4 a = *(const usv4*)&src[(long)eA*H1 + l*4];
        s0 += bf2f(a.x); s1 += bf2f(a.y); s2 += bf2f(a.z); s3 += bf2f(a.w);
      }
    } else {
      for (; j < re; ++j){
        int eA = (j < LCAP) ? lst[j] : lis_g[base + j];
        usv4 a = *(const usv4*)&src[(long)eA*H1 + l*4];
        s0 += bf2f(a.x); s1 += bf2f(a.y); s2 += bf2f(a.z); s3 += bf2f(a.w);
      }
    }
    float rd = 1.f / fmaxf((float)(re - rs), 1.f);
    usv4 o = { f2b(s0*rd), f2b(s1*rd), f2b(s2*rd), f2b(s3*rd) };
    *(usv4*)&a_s[r*PITCH + l*4] = o;
  }
}

template<int PITCH>
__device__ __forceinline__ void gather_h2(u16* a_s, const float* __restrict__ src,
    const int* lst, const int* roff, int base, const int* __restrict__ lis_g, int w, int l)
{
  for (int rr = 0; rr < 16; rr++){
    int r = w + rr*4;
    int rs = roff[r] - base, re = roff[r+1] - base;
    float s0=0.f, s1=0.f;
    int j = rs;
    if (re <= LCAP){
      for (; j + 4 <= re; j += 4){
        int eA = lst[j], eB = lst[j+1], eC = lst[j+2], eD = lst[j+3];
        float2 a = *(const float2*)&src[(long)eA*H2 + l*2];
        float2 b = *(const float2*)&src[(long)eB*H2 + l*2];
        float2 c = *(const float2*)&src[(long)eC*H2 + l*2];
        float2 d = *(const float2*)&src[(long)eD*H2 + l*2];
        s0 += (a.x+b.x) + (c.x+d.x);
        s1 += (a.y+b.y) + (c.y+d.y);
      }
      if (j + 2 <= re){
        int eA = lst[j], eB = lst[j+1]; j += 2;
        float2 a = *(const float2*)&src[(long)eA*H2 + l*2];
        float2 b = *(const float2*)&src[(long)eB*H2 + l*2];
        s0 += a.x + b.x; s1 += a.y + b.y;
      }
      if (j < re){
        int eA = lst[j];
        float2 a = *(const float2*)&src[(long)eA*H2 + l*2];
        s0 += a.x; s1 += a.y;
      }
    } else {
      for (; j < re; ++j){
        int eA = (j < LCAP) ? lst[j] : lis_g[base + j];
        float2 a = *(const float2*)&src[(long)eA*H2 + l*2];
        s0 += a.x; s1 += a.y;
      }
    }
    float rd = 1.f / fmaxf((float)(re - rs), 1.f);
    usv2 o = { f2b(s0*rd), f2b(s1*rd) };
    *(usv2*)&a_s[r*PITCH + l*2] = o;
  }
}

// ---------------- node block 1 ----------------
__global__ __launch_bounds__(256, 3) void node1_kernel(
    const float* __restrict__ nodes, const u16* __restrict__ e1b,
    const int* __restrict__ off, const int* __restrict__ lis,
    const u16* __restrict__ pWn1, const u16* __restrict__ pWin1, const u16* __restrict__ pWout1,
    const float* __restrict__ bn1, u16* __restrict__ n1b, float* __restrict__ n1p)
{
  __shared__ __align__(16) u16 a_s[64*APK];
  __shared__ int ilA[LCAP], ilB[LCAP];
  __shared__ int roff[65], roff2[65];
  __shared__ float cs_s[H1];
  __shared__ float bs[H1];
  const int t = threadIdx.x;
  const long n0 = (long)blockIdx.x * 64;
  const int w = t >> 6, l = t & 63, lr = l & 15, q = l >> 4;

  cs_s[t] = 0.f;
  bs[t] = bn1[t];
  if (t <= 64){
    long idx = n0 + t;
    roff [t] = (idx >= NN) ? NE     : off[idx];
    roff2[t] = (idx >= NN) ? 2*NE   : off[NN + idx];
  }
  __syncthreads();
  const int inb = roff[0],  in_total  = roff[64]  - inb;
  const int onb = roff2[0], out_total = roff2[64] - onb;
  for (int j = t; j < in_total  && j < LCAP; j += 256) ilA[j] = lis[inb + j];
  for (int j = t; j < out_total && j < LCAP; j += 256) ilB[j] = lis[onb + j];
  __syncthreads();

  f32v4 acc[16];
  #pragma unroll
  for (int nt = 0; nt < 16; nt++) acc[nt] = (f32v4){0.f,0.f,0.f,0.f};

  gather_h1<APK>(a_s, e1b, ilA, roff, inb, lis, w, l);
  __syncthreads();
  gemm_tiles<8,16,APK>(a_s, pWin1, w, l, acc);
  __syncthreads();

  gather_h1<APK>(a_s, e1b, ilB, roff2, onb, lis, w, l);
  __syncthreads();
  gemm_tiles<8,16,APK>(a_s, pWout1, w, l, acc);
  __syncthreads();

  stage_rows<3>(a_s, nodes, n0, t);
  __syncthreads();
  gemm_tiles<1,16,APK>(a_s, pWn1, w, l, acc);

  #pragma unroll
  for (int nt = 0; nt < 16; nt++){
    const float b = bs[nt*16 + lr];
    float part = 0.f;
    #pragma unroll
    for (int r = 0; r < 4; r++){
      const long n = n0 + w*16 + q*4 + r;
      float v = fmaxf(acc[nt][r] + b, 0.f);
      acc[nt][r] = v;
      if (n < NN) part += v;
    }
    atomicAdd(&cs_s[nt*16 + lr], part);
  }
  #pragma unroll
  for (int r = 0; r < 4; r++){
    const int m = w*16 + q*4 + r;
    const long n = n0 + m;
    if (n < NN){
      usv8 o0, o1;
      #pragma unroll
      for (int h = 0; h < 8; h++){ o0[h] = f2b(acc[h][r]); o1[h] = f2b(acc[8+h][r]); }
      *(usv8*)&n1b[n*H1 + lr*16]     = o0;
      *(usv8*)&n1b[n*H1 + lr*16 + 8] = o1;
    }
  }
  __syncthreads();
  atomicAdd(&n1p[(blockIdx.x & (NPART-1))*H1 + t], cs_s[t]);
}

// ---------------- node block 2 ----------------
__global__ __launch_bounds__(256, 4) void node2_kernel(
    const u16* __restrict__ n1b, const float* __restrict__ e2f,
    const int* __restrict__ off, const int* __restrict__ lis,
    const u16* __restrict__ pWn2, const u16* __restrict__ pWin2, const u16* __restrict__ pWout2,
    const float* __restrict__ bn2, float* __restrict__ n2_out, float* __restrict__ n2p)
{
  __shared__ __align__(16) u16 a_s[64*AP2];
  __shared__ int ilA[LCAP], ilB[LCAP];
  __shared__ int roff[65], roff2[65];
  __shared__ float cs_s[H2];
  const int t = threadIdx.x;
  const long n0 = (long)blockIdx.x * 64;
  const int w = t >> 6, l = t & 63, lr = l & 15, q = l >> 4;

  if (t < H2) cs_s[t] = 0.f;
  if (t <= 64){
    long idx = n0 + t;
    roff [t] = (idx >= NN) ? NE     : off[idx];
    roff2[t] = (idx >= NN) ? 2*NE   : off[NN + idx];
  }
  __syncthreads();
  const int inb = roff[0],  in_total  = roff[64]  - inb;
  const int onb = roff2[0], out_total = roff2[64] - onb;
  for (int j = t; j < in_total  && j < LCAP; j += 256) ilA[j] = lis[inb + j];
  for (int j = t; j < out_total && j < LCAP; j += 256) ilB[j] = lis[onb + j];
  __syncthreads();

  f32v4 acc[8];
  #pragma unroll
  for (int nt = 0; nt < 8; nt++) acc[nt] = (f32v4){0.f,0.f,0.f,0.f};

  // A = n1 (permuted bf16 rows), K=256 as two K=128 half-tiles; pWn2 packed with g1
  for (int h = 0; h < 2; h++){
    for (int idx = t; idx < 64*16; idx += 256){
      int row = idx >> 4, ch = idx & 15;
      long n = n0 + row;
      usv8 v = (usv8){0,0,0,0,0,0,0,0};
      if (n < NN) v = *(const usv8*)&n1b[n*H1 + h*128 + ch*8];
      *(usv8*)&a_s[row*AP2 + ch*8] = v;
    }
    __syncthreads();
    gemm_tiles<4,8,AP2>(a_s, pWn2 + h*(4*8*64*8), w, l, acc);
    __syncthreads();
  }

  gather_h2<AP2>(a_s, e2f, ilA, roff, inb, lis, w, l);
  __syncthreads();
  gemm_tiles<4,8,AP2>(a_s, pWin2, w, l, acc);
  __syncthreads();

  gather_h2<AP2>(a_s, e2f, ilB, roff2, onb, lis, w, l);
  __syncthreads();
  gemm_tiles<4,8,AP2>(a_s, pWout2, w, l, acc);

  #pragma unroll
  for (int nt = 0; nt < 8; nt++){
    const int j = nt*16 + lr;
    const float b = bn2[j];
    float part = 0.f;
    #pragma unroll
    for (int r = 0; r < 4; r++){
      const int row = w*16 + q*4 + r;
      const long n = n0 + row;
      if (n < NN){
        float v = fmaxf(acc[nt][r] + b, 0.f);
        n2_out[n*H2 + j] = v;
        part += v;
      }
    }
    atomicAdd(&cs_s[j], part);
  }
  __syncthreads();
  if (t < H2) atomicAdd(&n2p[(blockIdx.x & (NPART-1))*H2 + t], cs_s[t]);
}

// ---------------- global updates (reduce NPART partial copies, then tiny GEMV) ----------------
__global__ void u1_kernel(const float* __restrict__ gu, const float* __restrict__ Wu1,
    const float* __restrict__ Wgn1, const float* __restrict__ Wge1, const float* __restrict__ bu1,
    const float* __restrict__ n1p, const float* __restrict__ e1p, float* __restrict__ u1v)
{
    __shared__ float ncs[H1], ecs[H1];
    const int j = threadIdx.x;
    float sn = 0.f, se = 0.f;
    #pragma unroll 8
    for (int c = 0; c < NPART; c++){ sn += n1p[c*H1 + j]; se += e1p[c*H1 + j]; }
    ncs[j] = sn; ecs[j] = se;
    __syncthreads();
    float acc = bu1[j];
    #pragma unroll
    for (int k = 0; k < FG; k++) acc += gu[k] * Wu1[k*H1 + j];
    for (int k = 0; k < H1; k++) acc += (ncs[k] * (1.f/NN)) * Wgn1[k*H1 + j];
    for (int k = 0; k < H1; k++) acc += (ecs[k] * (1.f/NE)) * Wge1[k*H1 + j];
    u1v[j] = fmaxf(acc, 0.f);
}

__global__ void u2_kernel(const float* __restrict__ u1v, const float* __restrict__ Wu2,
    const float* __restrict__ Wgn2, const float* __restrict__ Wge2, const float* __restrict__ bu2,
    const float* __restrict__ n2p, const float* __restrict__ e2p, float* __restrict__ u2_out)
{
    __shared__ float ncs[H2], ecs[H2];
    const int j = threadIdx.x;
    float sn = 0.f, se = 0.f;
    #pragma unroll 8
    for (int c = 0; c < NPART; c++){ sn += n2p[c*H2 + j]; se += e2p[c*H2 + j]; }
    ncs[j] = sn; ecs[j] = se;
    __syncthreads();
    float acc = bu2[j];
    for (int k = 0; k < H1; k++) acc += u1v[k] * Wu2[k*H2 + j];
    for (int k = 0; k < H2; k++) acc += (ncs[k] * (1.f/NN)) * Wgn2[k*H2 + j];
    for (int k = 0; k < H2; k++) acc += (ecs[k] * (1.f/NE)) * Wge2[k*H2 + j];
    u2_out[j] = fmaxf(acc, 0.f);
}

// ---------------- launcher ----------------
extern "C" void kernel_launch(void* const* d_in, const int* in_sizes, int n_in,
                              void* d_out, int out_size, void* d_ws, size_t ws_size,
                              hipStream_t stream)
{
    (void)in_sizes; (void)n_in; (void)out_size; (void)ws_size;
    const float* nodes = (const float*)d_in[0];
    const float* edges = (const float*)d_in[1];
    const float* gu    = (const float*)d_in[2];
    const int* senders   = (const int*)d_in[3];
    const int* receivers = (const int*)d_in[4];
    const float* We1  = (const float*)d_in[5];  const float* be1 = (const float*)d_in[6];
    const float* Wn1  = (const float*)d_in[7];  const float* Win1= (const float*)d_in[8];
    const float* Wout1= (const float*)d_in[9];  const float* bn1 = (const float*)d_in[10];
    const float* Wu1  = (const float*)d_in[11]; const float* Wgn1= (const float*)d_in[12];
    const float* Wge1 = (const float*)d_in[13]; const float* bu1 = (const float*)d_in[14];
    const float* We2  = (const float*)d_in[15]; const float* be2 = (const float*)d_in[16];
    const float* Wn2  = (const float*)d_in[17]; const float* Win2= (const float*)d_in[18];
    const float* Wout2= (const float*)d_in[19]; const float* bn2 = (const float*)d_in[20];
    const float* Wu2  = (const float*)d_in[21]; const float* Wgn2= (const float*)d_in[22];
    const float* Wge2 = (const float*)d_in[23]; const float* bu2 = (const float*)d_in[24];

    float* ws = (float*)d_ws;
    size_t o = 0;
    int*   cnt    = (int*)(ws + o);  o += M2;            // zeroed
    float* e1p    = ws + o;          o += (size_t)NPART*H1;  // zeroed
    float* n1p    = ws + o;          o += (size_t)NPART*H1;  // zeroed
    float* e2p    = ws + o;          o += (size_t)NPART*H2;  // zeroed
    float* n2p    = ws + o;          o += (size_t)NPART*H2;  // zeroed
    const size_t zero_bytes = o * sizeof(float);
    float* u1v    = ws + o;          o += 256;
    int*   off    = (int*)(ws + o);  o += M2;
    int*   pos_in = (int*)(ws + o);  o += NE;
    int*   pos_out= (int*)(ws + o);  o += NE;
    int*   lis    = (int*)(ws + o);  o += 2*NE;
    int*   btot   = (int*)(ws + o);  o += 400;

    u16* pbase = (u16*)(ws + o);
    size_t po = 0;
    u16* pWin1 = pbase + po;  po += (size_t)H1*H1;
    u16* pWout1= pbase + po;  po += (size_t)H1*H1;
    u16* pWn1  = pbase + po;  po += (size_t)FN*H1;
    u16* pWe1  = pbase + po;  po += (size_t)32*H1;   // K padded 16->32
    u16* pWe2  = pbase + po;  po += (size_t)H1*H2;
    u16* pWn2  = pbase + po;  po += (size_t)H1*H2;
    u16* pWin2 = pbase + po;  po += (size_t)H2*H2;
    u16* pWout2= pbase + po;  po += (size_t)H2*H2;
    o += (po + 1) / 2;

    u16* n1b = (u16*)(ws + o);       // NN*H1 bf16 = 25.6 MB (permuted cols)

    float* n2_out = (float*)d_out;
    float* e2f    = n2_out + (size_t)NN*H2;          // e2 region; also scratch for e1 (bf16)
    float* u2_out = n2_out + (size_t)(NN + NE)*H2;
    u16*   e1b    = (u16*)e2f;                       // e1 bf16 rows (permuted cols) until e2_kernel

    hipMemsetAsync(d_ws, 0, zero_bytes, stream);

    PackArgs pa;
    pa.d[0] = {Win1,  pWin1,  H1, H1, H1, 1};
    pa.d[1] = {Wout1, pWout1, H1, H1, H1, 1};
    pa.d[2] = {Wn1,   pWn1,   FN, H1, FN, 0};
    pa.d[3] = {We1,   pWe1,   32, H1, FE, 0};
    pa.d[4] = {We2,   pWe2,   H1, H2, H1, 1};
    pa.d[5] = {Wn2,   pWn2,   H1, H2, H1, 1};
    pa.d[6] = {Win2,  pWin2,  H2, H2, H2, 0};   // gather_h2 A-tile is CANONICAL -> no perm
    pa.d[7] = {Wout2, pWout2, H2, H2, H2, 0};   // gather_h2 A-tile is CANONICAL -> no perm
    int total_tiles = 0;
    for (int i = 0; i < 8; i++) total_tiles += (pa.d[i].K >> 5) * (pa.d[i].N >> 4);
    pack_weights<<<total_tiles, 64, 0, stream>>>(pa);

    const int EG = (NE + 255)/256;
    csr_count<<<EG, 256, 0, stream>>>(receivers, senders, cnt, pos_in, pos_out);
    scan_blocks<<<SCAN_B, 256, 0, stream>>>(cnt, off, btot);
    scan_tops<<<1, 256, 0, stream>>>(btot);
    scan_fix<<<SCAN_B, 256, 0, stream>>>(off, btot);
    csr_fill<<<EG, 256, 0, stream>>>(receivers, senders, off, pos_in, pos_out, lis);

    edge1_kernel<<<NE/64, 256, 0, stream>>>(edges, pWe1, be1, e1b, e1p);

    node1_kernel<<<(NN + 63)/64, 256, 0, stream>>>(nodes, e1b, off, lis,
        pWn1, pWin1, pWout1, bn1, n1b, n1p);

    u1_kernel<<<1, H1, 0, stream>>>(gu, Wu1, Wgn1, Wge1, bu1, n1p, e1p, u1v);

    e2_kernel<<<NE/64, 256, 0, stream>>>(e2f, pWe2, be2, e2p);

    node2_kernel<<<(NN + 63)/64, 256, 0, stream>>>(n1b, e2f, off, lis,
        pWn2, pWin2, pWout2, bn2, n2_out, n2p);

    u2_kernel<<<1, H2, 0, stream>>>(u1v, Wu2, Wgn2, Wge2, bu2, n2p, e2p, u2_out);
}

// Round 5
// 902.374 us; speedup vs baseline: 1.3732x; 1.1216x over previous
//
#include <hip/hip_runtime.h>
#include <hip/hip_bf16.h>
#include <stdint.h>

#define NN 50000
#define NE 400000
#define FN 32
#define FE 16
#define FG 16
#define H1 256
#define H2 128
#define M2 (2*NN)          // concatenated [in-counts, out-counts]
#define SCAN_B 391         // ceil(M2/256)
#define LCAP 1536          // staged edge-list capacity per tile per direction
#define NPART 256          // partial-sum copies for column sums (atomic spreading)

typedef unsigned short u16;
typedef __bf16 bfv8 __attribute__((ext_vector_type(8)));
typedef float f32v4 __attribute__((ext_vector_type(4)));
typedef u16 usv2 __attribute__((ext_vector_type(2)));
typedef u16 usv4 __attribute__((ext_vector_type(4)));
typedef u16 usv8 __attribute__((ext_vector_type(8)));

#define APK 264   // LDS pitch (bf16 elems): 528B rows (node1/e2: K=256 tiles)
#define AP2 136   // LDS pitch for node2's K=128 tiles
#define EP1 40    // LDS pitch for edge1's 64x32 tile

// Column-permuted storage for e1b / n1b (both workspace-only):
//   stored col c' = lr*16 + nt holds original col j = nt*16 + lr  (nibble swap, involution)
//   g1(c) = ((c&15)<<4) | (c>>4)
// Consumers whose A-tile preserves that permuted order pack weights with perm=1 (K-rows by g1).
// gather_h2 writes CANONICAL order (reads canonical e2f) -> Win2/Wout2 pack with perm=0.
// e2f stays canonical (harness output) -> swizzled-LDS transpose for vector stores.
//
// DRAIN RULE: __syncthreads() emits s_waitcnt vmcnt(0) -> never place a barrier after
// bulk global stores. All kernels issue their big stores AFTER the last barrier and
// end the wave with stores in flight.

__device__ __forceinline__ u16 f2b(float x){
  __hip_bfloat16 h = __float2bfloat16(x);
  return *reinterpret_cast<u16*>(&h);
}
__device__ __forceinline__ float bf2f(u16 u){
  union{uint32_t i; float f;} v; v.i = ((uint32_t)u) << 16; return v.f;
}

// ---------------- MFMA GEMM over LDS A-tile [row][k] and frag-packed B ----------------
template<int NCK, int NNT, int PITCH>
__device__ __forceinline__ void gemm_tiles(const u16* a_s, const u16* __restrict__ pB,
                                           int w, int l, f32v4* acc)
{
  const int lr = l & 15, q = l >> 4;
  const bfv8* bp = (const bfv8*)pB;
  for (int ck = 0; ck < NCK; ck++){
    bfv8 a = *(const bfv8*)&a_s[(w*16 + lr)*PITCH + ck*32 + q*8];
    #pragma unroll
    for (int nt = 0; nt < NNT; nt++){
      bfv8 b = bp[(ck*NNT + nt)*64 + l];
      acc[nt] = __builtin_amdgcn_mfma_f32_16x16x32_bf16(a, b, acc[nt], 0, 0, 0);
    }
  }
}

// stage 64 rows x (4<<C4PR_LOG2) f32 cols from global into LDS bf16 [row][k] (pitch APK)
template<int C4PR_LOG2>
__device__ __forceinline__ void stage_rows(u16* a_s, const float* __restrict__ src,
                                           long n0, int t)
{
  const int c4pr = 1 << C4PR_LOG2;
  for (int idx = t; idx < 64*c4pr; idx += 256){
    int row = idx >> C4PR_LOG2, c4 = idx & (c4pr - 1);
    long n = n0 + row;
    float x0=0.f, x1=0.f, x2=0.f, x3=0.f;
    if (n < NN){
      const float4 v = *(const float4*)&src[(n << (C4PR_LOG2 + 2)) + c4*4];
      x0 = v.x; x1 = v.y; x2 = v.z; x3 = v.w;
    }
    usv4 o; o.x = f2b(x0); o.y = f2b(x1); o.z = f2b(x2); o.w = f2b(x3);
    *(usv4*)&a_s[row*APK + c4*4] = o;
  }
}

// ---------------- weight pre-pack into MFMA fragment order ----------------
// perm: 0 = none, 1 = g1 (256-wide nibble swap on K index)
struct PD { const float* src; u16* dst; int K, N, Ks, perm; };
struct PackArgs { PD d[8]; };

__global__ __launch_bounds__(64) void pack_weights(PackArgs A){
  int b = blockIdx.x, l = threadIdx.x;
  int mi = 0, base = 0;
  for (; mi < 8; mi++){
    int tiles = (A.d[mi].K >> 5) * (A.d[mi].N >> 4);
    if (b < base + tiles) break;
    base += tiles;
  }
  const PD d = A.d[mi];
  const int tile = b - base;
  const int ntn = d.N >> 4;
  const int ck = tile / ntn, nt = tile % ntn;
  const int lr = l & 15, q = l >> 4;
  const int col = nt*16 + lr;
  usv8 o;
  #pragma unroll
  for (int j = 0; j < 8; j++){
    int k = ck*32 + q*8 + j;
    int sk = (d.perm == 1) ? (((k & 15) << 4) | (k >> 4)) : k;
    o[j] = (k < d.Ks) ? f2b(d.src[(long)sk * d.N + col]) : (u16)0;
  }
  *(usv8*)&d.dst[((long)tile*64 + l)*8] = o;
}

// ---------------- CSR build ----------------
__global__ __launch_bounds__(256) void csr_count(const int* __restrict__ recv,
    const int* __restrict__ send, int* cnt, int* pos_in, int* pos_out)
{
  int e = blockIdx.x*256 + threadIdx.x;
  if (e >= NE) return;
  pos_in [e] = atomicAdd(&cnt[recv[e]], 1);
  pos_out[e] = atomicAdd(&cnt[NN + send[e]], 1);
}

__global__ __launch_bounds__(256) void scan_blocks(const int* __restrict__ cnt,
    int* off, int* btot)
{
  __shared__ int s[256];
  int b = blockIdx.x, t = threadIdx.x;
  int i = b*256 + t;
  int v = (i < M2) ? cnt[i] : 0;
  s[t] = v; __syncthreads();
  int acc = v;
  for (int d = 1; d < 256; d <<= 1){
    int add = (t >= d) ? s[t-d] : 0;
    __syncthreads();
    acc += add; s[t] = acc;
    __syncthreads();
  }
  if (i < M2) off[i] = acc - v;     // block-local exclusive
  if (t == 255) btot[b] = acc;
}

__global__ __launch_bounds__(256) void scan_tops(int* btot){
  __shared__ int s[512], ts[256];
  int t = threadIdx.x;
  s[t]     = (t < SCAN_B) ? btot[t] : 0;
  s[256+t] = (256+t < SCAN_B) ? btot[256+t] : 0;
  __syncthreads();
  int a0 = s[2*t], a1 = s[2*t+1];
  int tot = a0 + a1;
  ts[t] = tot; __syncthreads();
  int acc = tot;
  for (int d = 1; d < 256; d <<= 1){
    int add = (t >= d) ? ts[t-d] : 0;
    __syncthreads();
    acc += add; ts[t] = acc;
    __syncthreads();
  }
  int excl = acc - tot;
  if (2*t   < SCAN_B) btot[2*t]   = excl;
  if (2*t+1 < SCAN_B) btot[2*t+1] = excl + a0;
}

__global__ __launch_bounds__(256) void scan_fix(int* off, const int* __restrict__ btot){
  int i = blockIdx.x*256 + threadIdx.x;
  if (i < M2) off[i] += btot[blockIdx.x];
}

__global__ __launch_bounds__(256) void csr_fill(const int* __restrict__ recv,
    const int* __restrict__ send, const int* __restrict__ off,
    const int* __restrict__ pos_in, const int* __restrict__ pos_out, int* lis)
{
  int e = blockIdx.x*256 + threadIdx.x;
  if (e >= NE) return;
  lis[off[recv[e]]      + pos_in [e]] = e;
  lis[off[NN + send[e]] + pos_out[e]] = e;
}

// ---------------- edge block 1: e1 = relu(edges@We1+be1), permuted cols -> e1b (bf16) ------------
__global__ __launch_bounds__(256) void edge1_kernel(const float* __restrict__ edges,
    const u16* __restrict__ pWe1, const float* __restrict__ be1,
    u16* __restrict__ e1b, float* __restrict__ e1p)
{
  __shared__ __align__(16) u16 a_es[64*EP1];
  __shared__ float cs_s[H1];
  __shared__ float bs[H1];
  const int t = threadIdx.x;
  const long e0 = (long)blockIdx.x * 64;
  const int w = t >> 6, l = t & 63, lr = l & 15, q = l >> 4;
  cs_s[t] = 0.f;
  bs[t] = be1[t];
  {
    int row = t >> 2, c4 = t & 3;
    float4 v = *(const float4*)&edges[(e0 + row)*FE + c4*4];
    usv4 o = { f2b(v.x), f2b(v.y), f2b(v.z), f2b(v.w) };
    *(usv4*)&a_es[row*EP1 + c4*4] = o;
    *(usv4*)&a_es[row*EP1 + 16 + c4*4] = (usv4){0,0,0,0};   // zero-pad k=16..31
  }
  __syncthreads();
  f32v4 acc[16];
  #pragma unroll
  for (int nt = 0; nt < 16; nt++) acc[nt] = (f32v4){0.f,0.f,0.f,0.f};
  gemm_tiles<1,16,EP1>(a_es, pWe1, w, l, acc);

  // bias+relu in place; column sums (shfl-reduce across q, then 1 LDS atomic per 4 lanes)
  #pragma unroll
  for (int nt = 0; nt < 16; nt++){
    const float b = bs[nt*16 + lr];
    float part = 0.f;
    #pragma unroll
    for (int r = 0; r < 4; r++){
      float v = fmaxf(acc[nt][r] + b, 0.f);
      acc[nt][r] = v; part += v;
    }
    part += __shfl_xor(part, 16);
    part += __shfl_xor(part, 32);
    if (q == 0) atomicAdd(&cs_s[nt*16 + lr], part);
  }
  // pack bf16 store data into regs (held across barrier)
  usv8 ob0[4], ob1[4];
  #pragma unroll
  for (int r = 0; r < 4; r++){
    #pragma unroll
    for (int h = 0; h < 8; h++){ ob0[r][h] = f2b(acc[h][r]); ob1[r][h] = f2b(acc[8+h][r]); }
  }
  __syncthreads();                    // vmcnt ~0 here: NO global stores issued yet
  atomicAdd(&e1p[(blockIdx.x & (NPART-1))*H1 + t], cs_s[t]);
  // bulk stores LAST; wave ends with stores in flight (no barrier drains them)
  #pragma unroll
  for (int r = 0; r < 4; r++){
    const int m = w*16 + q*4 + r;
    *(usv8*)&e1b[(e0 + m)*H1 + lr*16]     = ob0[r];
    *(usv8*)&e1b[(e0 + m)*H1 + lr*16 + 8] = ob1[r];
  }
}

// ---------------- edge block 2: in-place e1b (perm bf16 rows) -> e2 (canonical f32 rows) --------
__global__ __launch_bounds__(256) void e2_kernel(float* __restrict__ e2f,
    const u16* __restrict__ pWe2, const float* __restrict__ be2, float* __restrict__ e2p)
{
  __shared__ __align__(16) u16 a_s[64*APK];   // 33792B; aliased below as f32 out-tile (32768B)
  __shared__ float cs_s[H2];
  __shared__ float bs[H2];
  const int t = threadIdx.x;
  const long e0 = (long)blockIdx.x * 64;
  const int w = t >> 6, l = t & 63, lr = l & 15, q = l >> 4;
  if (t < H2){ cs_s[t] = 0.f; bs[t] = be2[t]; }
  const u16* e1u = (const u16*)e2f;
  for (int idx = t; idx < 64*32; idx += 256){
    int row = idx >> 5, ch = idx & 31;
    usv8 v = *(const usv8*)&e1u[(e0 + row)*H1 + ch*8];
    *(usv8*)&a_s[row*APK + ch*8] = v;
  }
  __syncthreads();   // all reads of this block's rows complete before overwrite below
  f32v4 acc[8];
  #pragma unroll
  for (int nt = 0; nt < 8; nt++) acc[nt] = (f32v4){0.f,0.f,0.f,0.f};
  gemm_tiles<8,8,APK>(a_s, pWe2, w, l, acc);

  #pragma unroll
  for (int nt = 0; nt < 8; nt++){
    const float b = bs[nt*16 + lr];
    float part = 0.f;
    #pragma unroll
    for (int r = 0; r < 4; r++){
      float v = fmaxf(acc[nt][r] + b, 0.f);
      acc[nt][r] = v; part += v;
    }
    part += __shfl_xor(part, 16);
    part += __shfl_xor(part, 32);
    if (q == 0) atomicAdd(&cs_s[nt*16 + lr], part);
  }
  __syncthreads();                 // all GEMM reads of a_s complete; vmcnt ~0
  // canonical-layout output via XOR-swizzled LDS transpose (2-way conflicts only)
  float* fl = (float*)a_s;
  #pragma unroll
  for (int r = 0; r < 4; r++){
    const int m = w*16 + q*4 + r;
    const int sw = (m & 7) * 4;
    #pragma unroll
    for (int nt = 0; nt < 8; nt++)
      fl[m*128 + ((nt*16 + lr) ^ sw)] = acc[nt][r];
  }
  __syncthreads();                 // LDS-only traffic; vmcnt ~0
  if (t < H2) atomicAdd(&e2p[(blockIdx.x & (NPART-1))*H2 + t], cs_s[t]);
  {
    const int row = t >> 2, c = t & 3;
    const int sw = (row & 7) * 4;
    #pragma unroll
    for (int k = 0; k < 8; k++){
      const int wi = (c*32 + k*4) ^ sw;
      float4 v = *(const float4*)&fl[row*128 + wi];
      *(float4*)&e2f[(e0 + row)*H2 + c*32 + k*4] = v;
    }
  }
}

// ---------------- gathers: mean of rows listed in CSR -> LDS A-tile ----------------
template<int PITCH>
__device__ __forceinline__ void gather_h1(u16* a_s, const u16* __restrict__ src,
    const int* lst, const int* roff, int base, const int* __restrict__ lis_g, int w, int l)
{
  for (int rr = 0; rr < 16; rr++){
    int r = w + rr*4;
    int rs = roff[r] - base, re = roff[r+1] - base;
    float s0=0.f, s1=0.f, s2=0.f, s3=0.f;
    int j = rs;
    if (re <= LCAP){
      for (; j + 4 <= re; j += 4){
        int eA = lst[j], eB = lst[j+1], eC = lst[j+2], eD = lst[j+3];
        usv4 a = *(const usv4*)&src[(long)eA*H1 + l*4];
        usv4 b = *(const usv4*)&src[(long)eB*H1 + l*4];
        usv4 c = *(const usv4*)&src[(long)eC*H1 + l*4];
        usv4 d = *(const usv4*)&src[(long)eD*H1 + l*4];
        s0 += (bf2f(a.x)+bf2f(b.x)) + (bf2f(c.x)+bf2f(d.x));
        s1 += (bf2f(a.y)+bf2f(b.y)) + (bf2f(c.y)+bf2f(d.y));
        s2 += (bf2f(a.z)+bf2f(b.z)) + (bf2f(c.z)+bf2f(d.z));
        s3 += (bf2f(a.w)+bf2f(b.w)) + (bf2f(c.w)+bf2f(d.w));
      }
      if (j + 2 <= re){
        int eA = lst[j], eB = lst[j+1]; j += 2;
        usv4 a = *(const usv4*)&src[(long)eA*H1 + l*4];
        usv4 b = *(const usv4*)&src[(long)eB*H1 + l*4];
        s0 += bf2f(a.x)+bf2f(b.x); s1 += bf2f(a.y)+bf2f(b.y);
        s2 += bf2f(a.z)+bf2f(b.z); s3 += bf2f(a.w)+bf2f(b.w);
      }
      if (j < re){
        int eA = lst[j];
        usv4 a = *(const usv4*)&src[(long)eA*H1 + l*4];
        s0 += bf2f(a.x); s1 += bf2f(a.y); s2 += bf2f(a.z); s3 += bf2f(a.w);
      }
    } else {
      for (; j < re; ++j){
        int eA = (j < LCAP) ? lst[j] : lis_g[base + j];
        usv4 a = *(const usv4*)&src[(long)eA*H1 + l*4];
        s0 += bf2f(a.x); s1 += bf2f(a.y); s2 += bf2f(a.z); s3 += bf2f(a.w);
      }
    }
    float rd = 1.f / fmaxf((float)(re - rs), 1.f);
    usv4 o = { f2b(s0*rd), f2b(s1*rd), f2b(s2*rd), f2b(s3*rd) };
    *(usv4*)&a_s[r*PITCH + l*4] = o;
  }
}

template<int PITCH>
__device__ __forceinline__ void gather_h2(u16* a_s, const float* __restrict__ src,
    const int* lst, const int* roff, int base, const int* __restrict__ lis_g, int w, int l)
{
  for (int rr = 0; rr < 16; rr++){
    int r = w + rr*4;
    int rs = roff[r] - base, re = roff[r+1] - base;
    float s0=0.f, s1=0.f;
    int j = rs;
    if (re <= LCAP){
      for (; j + 4 <= re; j += 4){
        int eA = lst[j], eB = lst[j+1], eC = lst[j+2], eD = lst[j+3];
        float2 a = *(const float2*)&src[(long)eA*H2 + l*2];
        float2 b = *(const float2*)&src[(long)eB*H2 + l*2];
        float2 c = *(const float2*)&src[(long)eC*H2 + l*2];
        float2 d = *(const float2*)&src[(long)eD*H2 + l*2];
        s0 += (a.x+b.x) + (c.x+d.x);
        s1 += (a.y+b.y) + (c.y+d.y);
      }
      if (j + 2 <= re){
        int eA = lst[j], eB = lst[j+1]; j += 2;
        float2 a = *(const float2*)&src[(long)eA*H2 + l*2];
        float2 b = *(const float2*)&src[(long)eB*H2 + l*2];
        s0 += a.x + b.x; s1 += a.y + b.y;
      }
      if (j < re){
        int eA = lst[j];
        float2 a = *(const float2*)&src[(long)eA*H2 + l*2];
        s0 += a.x; s1 += a.y;
      }
    } else {
      for (; j < re; ++j){
        int eA = (j < LCAP) ? lst[j] : lis_g[base + j];
        float2 a = *(const float2*)&src[(long)eA*H2 + l*2];
        s0 += a.x; s1 += a.y;
      }
    }
    float rd = 1.f / fmaxf((float)(re - rs), 1.f);
    usv2 o = { f2b(s0*rd), f2b(s1*rd) };
    *(usv2*)&a_s[r*PITCH + l*2] = o;
  }
}

// ---------------- node block 1 ----------------
__global__ __launch_bounds__(256, 3) void node1_kernel(
    const float* __restrict__ nodes, const u16* __restrict__ e1b,
    const int* __restrict__ off, const int* __restrict__ lis,
    const u16* __restrict__ pWn1, const u16* __restrict__ pWin1, const u16* __restrict__ pWout1,
    const float* __restrict__ bn1, u16* __restrict__ n1b, float* __restrict__ n1p)
{
  __shared__ __align__(16) u16 a_s[64*APK];
  __shared__ int ilA[LCAP], ilB[LCAP];
  __shared__ int roff[65], roff2[65];
  __shared__ float cs_s[H1];
  __shared__ float bs[H1];
  const int t = threadIdx.x;
  const long n0 = (long)blockIdx.x * 64;
  const int w = t >> 6, l = t & 63, lr = l & 15, q = l >> 4;

  cs_s[t] = 0.f;
  bs[t] = bn1[t];
  if (t <= 64){
    long idx = n0 + t;
    roff [t] = (idx >= NN) ? NE     : off[idx];
    roff2[t] = (idx >= NN) ? 2*NE   : off[NN + idx];
  }
  __syncthreads();
  const int inb = roff[0],  in_total  = roff[64]  - inb;
  const int onb = roff2[0], out_total = roff2[64] - onb;
  for (int j = t; j < in_total  && j < LCAP; j += 256) ilA[j] = lis[inb + j];
  for (int j = t; j < out_total && j < LCAP; j += 256) ilB[j] = lis[onb + j];
  __syncthreads();

  f32v4 acc[16];
  #pragma unroll
  for (int nt = 0; nt < 16; nt++) acc[nt] = (f32v4){0.f,0.f,0.f,0.f};

  gather_h1<APK>(a_s, e1b, ilA, roff, inb, lis, w, l);
  __syncthreads();
  gemm_tiles<8,16,APK>(a_s, pWin1, w, l, acc);
  __syncthreads();

  gather_h1<APK>(a_s, e1b, ilB, roff2, onb, lis, w, l);
  __syncthreads();
  gemm_tiles<8,16,APK>(a_s, pWout1, w, l, acc);
  __syncthreads();

  stage_rows<3>(a_s, nodes, n0, t);
  __syncthreads();
  gemm_tiles<1,16,APK>(a_s, pWn1, w, l, acc);

  #pragma unroll
  for (int nt = 0; nt < 16; nt++){
    const float b = bs[nt*16 + lr];
    float part = 0.f;
    #pragma unroll
    for (int r = 0; r < 4; r++){
      const long n = n0 + w*16 + q*4 + r;
      float v = fmaxf(acc[nt][r] + b, 0.f);
      acc[nt][r] = v;
      if (n < NN) part += v;
    }
    part += __shfl_xor(part, 16);
    part += __shfl_xor(part, 32);
    if (q == 0) atomicAdd(&cs_s[nt*16 + lr], part);
  }
  __syncthreads();                  // vmcnt ~0: n1b stores NOT issued yet
  atomicAdd(&n1p[(blockIdx.x & (NPART-1))*H1 + t], cs_s[t]);
  // bulk stores LAST
  #pragma unroll
  for (int r = 0; r < 4; r++){
    const int m = w*16 + q*4 + r;
    const long n = n0 + m;
    if (n < NN){
      usv8 o0, o1;
      #pragma unroll
      for (int h = 0; h < 8; h++){ o0[h] = f2b(acc[h][r]); o1[h] = f2b(acc[8+h][r]); }
      *(usv8*)&n1b[n*H1 + lr*16]     = o0;
      *(usv8*)&n1b[n*H1 + lr*16 + 8] = o1;
    }
  }
}

// ---------------- node block 2 ----------------
__global__ __launch_bounds__(256, 4) void node2_kernel(
    const u16* __restrict__ n1b, const float* __restrict__ e2f,
    const int* __restrict__ off, const int* __restrict__ lis,
    const u16* __restrict__ pWn2, const u16* __restrict__ pWin2, const u16* __restrict__ pWout2,
    const float* __restrict__ bn2, float* __restrict__ n2_out, float* __restrict__ n2p)
{
  __shared__ __align__(16) u16 a_s[64*AP2];
  __shared__ int ilA[LCAP], ilB[LCAP];
  __shared__ int roff[65], roff2[65];
  __shared__ float cs_s[H2];
  const int t = threadIdx.x;
  const long n0 = (long)blockIdx.x * 64;
  const int w = t >> 6, l = t & 63, lr = l & 15, q = l >> 4;

  if (t < H2) cs_s[t] = 0.f;
  if (t <= 64){
    long idx = n0 + t;
    roff [t] = (idx >= NN) ? NE     : off[idx];
    roff2[t] = (idx >= NN) ? 2*NE   : off[NN + idx];
  }
  __syncthreads();
  const int inb = roff[0],  in_total  = roff[64]  - inb;
  const int onb = roff2[0], out_total = roff2[64] - onb;
  for (int j = t; j < in_total  && j < LCAP; j += 256) ilA[j] = lis[inb + j];
  for (int j = t; j < out_total && j < LCAP; j += 256) ilB[j] = lis[onb + j];
  __syncthreads();

  f32v4 acc[8];
  #pragma unroll
  for (int nt = 0; nt < 8; nt++) acc[nt] = (f32v4){0.f,0.f,0.f,0.f};

  // A = n1 (permuted bf16 rows), K=256 as two K=128 half-tiles; pWn2 packed with g1
  for (int h = 0; h < 2; h++){
    for (int idx = t; idx < 64*16; idx += 256){
      int row = idx >> 4, ch = idx & 15;
      long n = n0 + row;
      usv8 v = (usv8){0,0,0,0,0,0,0,0};
      if (n < NN) v = *(const usv8*)&n1b[n*H1 + h*128 + ch*8];
      *(usv8*)&a_s[row*AP2 + ch*8] = v;
    }
    __syncthreads();
    gemm_tiles<4,8,AP2>(a_s, pWn2 + h*(4*8*64*8), w, l, acc);
    __syncthreads();
  }

  gather_h2<AP2>(a_s, e2f, ilA, roff, inb, lis, w, l);
  __syncthreads();
  gemm_tiles<4,8,AP2>(a_s, pWin2, w, l, acc);
  __syncthreads();

  gather_h2<AP2>(a_s, e2f, ilB, roff2, onb, lis, w, l);
  __syncthreads();
  gemm_tiles<4,8,AP2>(a_s, pWout2, w, l, acc);

  #pragma unroll
  for (int nt = 0; nt < 8; nt++){
    const float b = bn2[nt*16 + lr];
    float part = 0.f;
    #pragma unroll
    for (int r = 0; r < 4; r++){
      const long n = n0 + w*16 + q*4 + r;
      float v = fmaxf(acc[nt][r] + b, 0.f);
      acc[nt][r] = v;
      if (n < NN) part += v;
    }
    part += __shfl_xor(part, 16);
    part += __shfl_xor(part, 32);
    if (q == 0) atomicAdd(&cs_s[nt*16 + lr], part);
  }
  __syncthreads();                  // vmcnt ~0: n2 stores NOT issued yet
  if (t < H2) atomicAdd(&n2p[(blockIdx.x & (NPART-1))*H2 + t], cs_s[t]);
  // stores LAST
  #pragma unroll
  for (int nt = 0; nt < 8; nt++){
    const int j = nt*16 + lr;
    #pragma unroll
    for (int r = 0; r < 4; r++){
      const long n = n0 + w*16 + q*4 + r;
      if (n < NN) n2_out[n*H2 + j] = acc[nt][r];
    }
  }
}

// ---------------- global updates (reduce NPART partial copies, then tiny GEMV) ----------------
__global__ void u1_kernel(const float* __restrict__ gu, const float* __restrict__ Wu1,
    const float* __restrict__ Wgn1, const float* __restrict__ Wge1, const float* __restrict__ bu1,
    const float* __restrict__ n1p, const float* __restrict__ e1p, float* __restrict__ u1v)
{
    __shared__ float ncs[H1], ecs[H1];
    const int j = threadIdx.x;
    float sn = 0.f, se = 0.f;
    #pragma unroll 8
    for (int c = 0; c < NPART; c++){ sn += n1p[c*H1 + j]; se += e1p[c*H1 + j]; }
    ncs[j] = sn; ecs[j] = se;
    __syncthreads();
    float acc = bu1[j];
    #pragma unroll
    for (int k = 0; k < FG; k++) acc += gu[k] * Wu1[k*H1 + j];
    for (int k = 0; k < H1; k++) acc += (ncs[k] * (1.f/NN)) * Wgn1[k*H1 + j];
    for (int k = 0; k < H1; k++) acc += (ecs[k] * (1.f/NE)) * Wge1[k*H1 + j];
    u1v[j] = fmaxf(acc, 0.f);
}

__global__ void u2_kernel(const float* __restrict__ u1v, const float* __restrict__ Wu2,
    const float* __restrict__ Wgn2, const float* __restrict__ Wge2, const float* __restrict__ bu2,
    const float* __restrict__ n2p, const float* __restrict__ e2p, float* __restrict__ u2_out)
{
    __shared__ float ncs[H2], ecs[H2];
    const int j = threadIdx.x;
    float sn = 0.f, se = 0.f;
    #pragma unroll 8
    for (int c = 0; c < NPART; c++){ sn += n2p[c*H2 + j]; se += e2p[c*H2 + j]; }
    ncs[j] = sn; ecs[j] = se;
    __syncthreads();
    float acc = bu2[j];
    for (int k = 0; k < H1; k++) acc += u1v[k] * Wu2[k*H2 + j];
    for (int k = 0; k < H2; k++) acc += (ncs[k] * (1.f/NN)) * Wgn2[k*H2 + j];
    for (int k = 0; k < H2; k++) acc += (ecs[k] * (1.f/NE)) * Wge2[k*H2 + j];
    u2_out[j] = fmaxf(acc, 0.f);
}

// ---------------- launcher ----------------
extern "C" void kernel_launch(void* const* d_in, const int* in_sizes, int n_in,
                              void* d_out, int out_size, void* d_ws, size_t ws_size,
                              hipStream_t stream)
{
    (void)in_sizes; (void)n_in; (void)out_size; (void)ws_size;
    const float* nodes = (const float*)d_in[0];
    const float* edges = (const float*)d_in[1];
    const float* gu    = (const float*)d_in[2];
    const int* senders   = (const int*)d_in[3];
    const int* receivers = (const int*)d_in[4];
    const float* We1  = (const float*)d_in[5];  const float* be1 = (const float*)d_in[6];
    const float* Wn1  = (const float*)d_in[7];  const float* Win1= (const float*)d_in[8];
    const float* Wout1= (const float*)d_in[9];  const float* bn1 = (const float*)d_in[10];
    const float* Wu1  = (const float*)d_in[11]; const float* Wgn1= (const float*)d_in[12];
    const float* Wge1 = (const float*)d_in[13]; const float* bu1 = (const float*)d_in[14];
    const float* We2  = (const float*)d_in[15]; const float* be2 = (const float*)d_in[16];
    const float* Wn2  = (const float*)d_in[17]; const float* Win2= (const float*)d_in[18];
    const float* Wout2= (const float*)d_in[19]; const float* bn2 = (const float*)d_in[20];
    const float* Wu2  = (const float*)d_in[21]; const float* Wgn2= (const float*)d_in[22];
    const float* Wge2 = (const float*)d_in[23]; const float* bu2 = (const float*)d_in[24];

    float* ws = (float*)d_ws;
    size_t o = 0;
    int*   cnt    = (int*)(ws + o);  o += M2;            // zeroed
    float* e1p    = ws + o;          o += (size_t)NPART*H1;  // zeroed
    float* n1p    = ws + o;          o += (size_t)NPART*H1;  // zeroed
    float* e2p    = ws + o;          o += (size_t)NPART*H2;  // zeroed
    float* n2p    = ws + o;          o += (size_t)NPART*H2;  // zeroed
    const size_t zero_bytes = o * sizeof(float);
    float* u1v    = ws + o;          o += 256;
    int*   off    = (int*)(ws + o);  o += M2;
    int*   pos_in = (int*)(ws + o);  o += NE;
    int*   pos_out= (int*)(ws + o);  o += NE;
    int*   lis    = (int*)(ws + o);  o += 2*NE;
    int*   btot   = (int*)(ws + o);  o += 400;

    u16* pbase = (u16*)(ws + o);
    size_t po = 0;
    u16* pWin1 = pbase + po;  po += (size_t)H1*H1;
    u16* pWout1= pbase + po;  po += (size_t)H1*H1;
    u16* pWn1  = pbase + po;  po += (size_t)FN*H1;
    u16* pWe1  = pbase + po;  po += (size_t)32*H1;   // K padded 16->32
    u16* pWe2  = pbase + po;  po += (size_t)H1*H2;
    u16* pWn2  = pbase + po;  po += (size_t)H1*H2;
    u16* pWin2 = pbase + po;  po += (size_t)H2*H2;
    u16* pWout2= pbase + po;  po += (size_t)H2*H2;
    o += (po + 1) / 2;

    u16* n1b = (u16*)(ws + o);       // NN*H1 bf16 = 25.6 MB (permuted cols)

    float* n2_out = (float*)d_out;
    float* e2f    = n2_out + (size_t)NN*H2;          // e2 region; also scratch for e1 (bf16)
    float* u2_out = n2_out + (size_t)(NN + NE)*H2;
    u16*   e1b    = (u16*)e2f;                       // e1 bf16 rows (permuted cols) until e2_kernel

    hipMemsetAsync(d_ws, 0, zero_bytes, stream);

    PackArgs pa;
    pa.d[0] = {Win1,  pWin1,  H1, H1, H1, 1};
    pa.d[1] = {Wout1, pWout1, H1, H1, H1, 1};
    pa.d[2] = {Wn1,   pWn1,   FN, H1, FN, 0};
    pa.d[3] = {We1,   pWe1,   32, H1, FE, 0};
    pa.d[4] = {We2,   pWe2,   H1, H2, H1, 1};
    pa.d[5] = {Wn2,   pWn2,   H1, H2, H1, 1};
    pa.d[6] = {Win2,  pWin2,  H2, H2, H2, 0};   // gather_h2 A-tile is CANONICAL -> no perm
    pa.d[7] = {Wout2, pWout2, H2, H2, H2, 0};   // gather_h2 A-tile is CANONICAL -> no perm
    int total_tiles = 0;
    for (int i = 0; i < 8; i++) total_tiles += (pa.d[i].K >> 5) * (pa.d[i].N >> 4);
    pack_weights<<<total_tiles, 64, 0, stream>>>(pa);

    const int EG = (NE + 255)/256;
    csr_count<<<EG, 256, 0, stream>>>(receivers, senders, cnt, pos_in, pos_out);
    scan_blocks<<<SCAN_B, 256, 0, stream>>>(cnt, off, btot);
    scan_tops<<<1, 256, 0, stream>>>(btot);
    scan_fix<<<SCAN_B, 256, 0, stream>>>(off, btot);
    csr_fill<<<EG, 256, 0, stream>>>(receivers, senders, off, pos_in, pos_out, lis);

    edge1_kernel<<<NE/64, 256, 0, stream>>>(edges, pWe1, be1, e1b, e1p);

    node1_kernel<<<(NN + 63)/64, 256, 0, stream>>>(nodes, e1b, off, lis,
        pWn1, pWin1, pWout1, bn1, n1b, n1p);

    u1_kernel<<<1, H1, 0, stream>>>(gu, Wu1, Wgn1, Wge1, bu1, n1p, e1p, u1v);

    e2_kernel<<<NE/64, 256, 0, stream>>>(e2f, pWe2, be2, e2p);

    node2_kernel<<<(NN + 63)/64, 256, 0, stream>>>(n1b, e2f, off, lis,
        pWn2, pWin2, pWout2, bn2, n2_out, n2p);

    u2_kernel<<<1, H2, 0, stream>>>(u1v, Wu2, Wgn2, Wge2, bu2, n2p, e2p, u2_out);
}

// Round 6
// 882.982 us; speedup vs baseline: 1.4034x; 1.0220x over previous
//
#include <hip/hip_runtime.h>
#include <hip/hip_bf16.h>
#include <stdint.h>

#define NN 50000
#define NE 400000
#define FN 32
#define FE 16
#define FG 16
#define H1 256
#define H2 128
#define M2 (2*NN)          // concatenated [in-counts, out-counts]
#define SCAN_B 391         // ceil(M2/256)
#define NPART 256          // partial-sum copies for column sums (atomic spreading)

typedef unsigned short u16;
typedef __bf16 bfv8 __attribute__((ext_vector_type(8)));
typedef float f32v4 __attribute__((ext_vector_type(4)));
typedef u16 usv2 __attribute__((ext_vector_type(2)));
typedef u16 usv4 __attribute__((ext_vector_type(4)));
typedef u16 usv8 __attribute__((ext_vector_type(8)));

#define APK 264   // LDS pitch (bf16 elems): 528B rows (node1/e2: K=256 tiles)
#define AP2 136   // LDS pitch for node2's K=128 tiles
#define EP1 40    // LDS pitch for edge1's 64x32 tile

// Column-permuted storage for e1b / n1b (both workspace-only):
//   stored col c' = lr*16 + nt holds original col j = nt*16 + lr  (nibble swap, involution)
//   g1(c) = ((c&15)<<4) | (c>>4)
// Consumers whose A-tile preserves that permuted order pack weights with perm=1 (K-rows by g1).
// gather_h2 writes CANONICAL order (reads canonical e2f) -> Win2/Wout2 pack with perm=0.
// e2f stays canonical (harness output) -> swizzled-LDS transpose for vector stores.
//
// DRAIN RULE: __syncthreads() emits s_waitcnt vmcnt(0) -> never place a barrier after
// bulk global stores. All kernels issue their big stores AFTER the last barrier and
// end the wave with stores in flight.
//
// GATHER (this round): no LDS index lists. Indices are read straight from lis (wave-uniform
// broadcast; ~4KB/block contiguous -> L2-hit). Depth-8 pipeline: 8 independent {idx,row}
// loads in flight covers a mean-degree-8 row in ONE latency exposure. Freed LDS lifts
// node1 to 4 blocks/CU (was 3, LDS-bound).

__device__ __forceinline__ u16 f2b(float x){
  __hip_bfloat16 h = __float2bfloat16(x);
  return *reinterpret_cast<u16*>(&h);
}
__device__ __forceinline__ float bf2f(u16 u){
  union{uint32_t i; float f;} v; v.i = ((uint32_t)u) << 16; return v.f;
}

// ---------------- MFMA GEMM over LDS A-tile [row][k] and frag-packed B ----------------
template<int NCK, int NNT, int PITCH>
__device__ __forceinline__ void gemm_tiles(const u16* a_s, const u16* __restrict__ pB,
                                           int w, int l, f32v4* acc)
{
  const int lr = l & 15, q = l >> 4;
  const bfv8* bp = (const bfv8*)pB;
  for (int ck = 0; ck < NCK; ck++){
    bfv8 a = *(const bfv8*)&a_s[(w*16 + lr)*PITCH + ck*32 + q*8];
    #pragma unroll
    for (int nt = 0; nt < NNT; nt++){
      bfv8 b = bp[(ck*NNT + nt)*64 + l];
      acc[nt] = __builtin_amdgcn_mfma_f32_16x16x32_bf16(a, b, acc[nt], 0, 0, 0);
    }
  }
}

// stage 64 rows x (4<<C4PR_LOG2) f32 cols from global into LDS bf16 [row][k] (pitch APK)
template<int C4PR_LOG2>
__device__ __forceinline__ void stage_rows(u16* a_s, const float* __restrict__ src,
                                           long n0, int t)
{
  const int c4pr = 1 << C4PR_LOG2;
  for (int idx = t; idx < 64*c4pr; idx += 256){
    int row = idx >> C4PR_LOG2, c4 = idx & (c4pr - 1);
    long n = n0 + row;
    float x0=0.f, x1=0.f, x2=0.f, x3=0.f;
    if (n < NN){
      const float4 v = *(const float4*)&src[(n << (C4PR_LOG2 + 2)) + c4*4];
      x0 = v.x; x1 = v.y; x2 = v.z; x3 = v.w;
    }
    usv4 o; o.x = f2b(x0); o.y = f2b(x1); o.z = f2b(x2); o.w = f2b(x3);
    *(usv4*)&a_s[row*APK + c4*4] = o;
  }
}

// ---------------- weight pre-pack into MFMA fragment order ----------------
// perm: 0 = none, 1 = g1 (256-wide nibble swap on K index)
struct PD { const float* src; u16* dst; int K, N, Ks, perm; };
struct PackArgs { PD d[8]; };

__global__ __launch_bounds__(64) void pack_weights(PackArgs A){
  int b = blockIdx.x, l = threadIdx.x;
  int mi = 0, base = 0;
  for (; mi < 8; mi++){
    int tiles = (A.d[mi].K >> 5) * (A.d[mi].N >> 4);
    if (b < base + tiles) break;
    base += tiles;
  }
  const PD d = A.d[mi];
  const int tile = b - base;
  const int ntn = d.N >> 4;
  const int ck = tile / ntn, nt = tile % ntn;
  const int lr = l & 15, q = l >> 4;
  const int col = nt*16 + lr;
  usv8 o;
  #pragma unroll
  for (int j = 0; j < 8; j++){
    int k = ck*32 + q*8 + j;
    int sk = (d.perm == 1) ? (((k & 15) << 4) | (k >> 4)) : k;
    o[j] = (k < d.Ks) ? f2b(d.src[(long)sk * d.N + col]) : (u16)0;
  }
  *(usv8*)&d.dst[((long)tile*64 + l)*8] = o;
}

// ---------------- CSR build ----------------
__global__ __launch_bounds__(256) void csr_count(const int* __restrict__ recv,
    const int* __restrict__ send, int* cnt, int* pos_in, int* pos_out)
{
  int e = blockIdx.x*256 + threadIdx.x;
  if (e >= NE) return;
  pos_in [e] = atomicAdd(&cnt[recv[e]], 1);
  pos_out[e] = atomicAdd(&cnt[NN + send[e]], 1);
}

__global__ __launch_bounds__(256) void scan_blocks(const int* __restrict__ cnt,
    int* off, int* btot)
{
  __shared__ int s[256];
  int b = blockIdx.x, t = threadIdx.x;
  int i = b*256 + t;
  int v = (i < M2) ? cnt[i] : 0;
  s[t] = v; __syncthreads();
  int acc = v;
  for (int d = 1; d < 256; d <<= 1){
    int add = (t >= d) ? s[t-d] : 0;
    __syncthreads();
    acc += add; s[t] = acc;
    __syncthreads();
  }
  if (i < M2) off[i] = acc - v;     // block-local exclusive
  if (t == 255) btot[b] = acc;
}

__global__ __launch_bounds__(256) void scan_tops(int* btot){
  __shared__ int s[512], ts[256];
  int t = threadIdx.x;
  s[t]     = (t < SCAN_B) ? btot[t] : 0;
  s[256+t] = (256+t < SCAN_B) ? btot[256+t] : 0;
  __syncthreads();
  int a0 = s[2*t], a1 = s[2*t+1];
  int tot = a0 + a1;
  ts[t] = tot; __syncthreads();
  int acc = tot;
  for (int d = 1; d < 256; d <<= 1){
    int add = (t >= d) ? ts[t-d] : 0;
    __syncthreads();
    acc += add; ts[t] = acc;
    __syncthreads();
  }
  int excl = acc - tot;
  if (2*t   < SCAN_B) btot[2*t]   = excl;
  if (2*t+1 < SCAN_B) btot[2*t+1] = excl + a0;
}

__global__ __launch_bounds__(256) void scan_fix(int* off, const int* __restrict__ btot){
  int i = blockIdx.x*256 + threadIdx.x;
  if (i < M2) off[i] += btot[blockIdx.x];
}

__global__ __launch_bounds__(256) void csr_fill(const int* __restrict__ recv,
    const int* __restrict__ send, const int* __restrict__ off,
    const int* __restrict__ pos_in, const int* __restrict__ pos_out, int* lis)
{
  int e = blockIdx.x*256 + threadIdx.x;
  if (e >= NE) return;
  lis[off[recv[e]]      + pos_in [e]] = e;
  lis[off[NN + send[e]] + pos_out[e]] = e;
}

// ---------------- edge block 1: e1 = relu(edges@We1+be1), permuted cols -> e1b (bf16) ------------
__global__ __launch_bounds__(256) void edge1_kernel(const float* __restrict__ edges,
    const u16* __restrict__ pWe1, const float* __restrict__ be1,
    u16* __restrict__ e1b, float* __restrict__ e1p)
{
  __shared__ __align__(16) u16 a_es[64*EP1];
  __shared__ float cs_s[H1];
  __shared__ float bs[H1];
  const int t = threadIdx.x;
  const long e0 = (long)blockIdx.x * 64;
  const int w = t >> 6, l = t & 63, lr = l & 15, q = l >> 4;
  cs_s[t] = 0.f;
  bs[t] = be1[t];
  {
    int row = t >> 2, c4 = t & 3;
    float4 v = *(const float4*)&edges[(e0 + row)*FE + c4*4];
    usv4 o = { f2b(v.x), f2b(v.y), f2b(v.z), f2b(v.w) };
    *(usv4*)&a_es[row*EP1 + c4*4] = o;
    *(usv4*)&a_es[row*EP1 + 16 + c4*4] = (usv4){0,0,0,0};   // zero-pad k=16..31
  }
  __syncthreads();
  f32v4 acc[16];
  #pragma unroll
  for (int nt = 0; nt < 16; nt++) acc[nt] = (f32v4){0.f,0.f,0.f,0.f};
  gemm_tiles<1,16,EP1>(a_es, pWe1, w, l, acc);

  // bias+relu in place; column sums (shfl-reduce across q, then 1 LDS atomic per 4 lanes)
  #pragma unroll
  for (int nt = 0; nt < 16; nt++){
    const float b = bs[nt*16 + lr];
    float part = 0.f;
    #pragma unroll
    for (int r = 0; r < 4; r++){
      float v = fmaxf(acc[nt][r] + b, 0.f);
      acc[nt][r] = v; part += v;
    }
    part += __shfl_xor(part, 16);
    part += __shfl_xor(part, 32);
    if (q == 0) atomicAdd(&cs_s[nt*16 + lr], part);
  }
  // pack bf16 store data into regs (held across barrier)
  usv8 ob0[4], ob1[4];
  #pragma unroll
  for (int r = 0; r < 4; r++){
    #pragma unroll
    for (int h = 0; h < 8; h++){ ob0[r][h] = f2b(acc[h][r]); ob1[r][h] = f2b(acc[8+h][r]); }
  }
  __syncthreads();                    // vmcnt ~0 here: NO global stores issued yet
  atomicAdd(&e1p[(blockIdx.x & (NPART-1))*H1 + t], cs_s[t]);
  // bulk stores LAST; wave ends with stores in flight (no barrier drains them)
  #pragma unroll
  for (int r = 0; r < 4; r++){
    const int m = w*16 + q*4 + r;
    *(usv8*)&e1b[(e0 + m)*H1 + lr*16]     = ob0[r];
    *(usv8*)&e1b[(e0 + m)*H1 + lr*16 + 8] = ob1[r];
  }
}

// ---------------- edge block 2: in-place e1b (perm bf16 rows) -> e2 (canonical f32 rows) --------
__global__ __launch_bounds__(256) void e2_kernel(float* __restrict__ e2f,
    const u16* __restrict__ pWe2, const float* __restrict__ be2, float* __restrict__ e2p)
{
  __shared__ __align__(16) u16 a_s[64*APK];   // 33792B; aliased below as f32 out-tile (32768B)
  __shared__ float cs_s[H2];
  __shared__ float bs[H2];
  const int t = threadIdx.x;
  const long e0 = (long)blockIdx.x * 64;
  const int w = t >> 6, l = t & 63, lr = l & 15, q = l >> 4;
  if (t < H2){ cs_s[t] = 0.f; bs[t] = be2[t]; }
  const u16* e1u = (const u16*)e2f;
  for (int idx = t; idx < 64*32; idx += 256){
    int row = idx >> 5, ch = idx & 31;
    usv8 v = *(const usv8*)&e1u[(e0 + row)*H1 + ch*8];
    *(usv8*)&a_s[row*APK + ch*8] = v;
  }
  __syncthreads();   // all reads of this block's rows complete before overwrite below
  f32v4 acc[8];
  #pragma unroll
  for (int nt = 0; nt < 8; nt++) acc[nt] = (f32v4){0.f,0.f,0.f,0.f};
  gemm_tiles<8,8,APK>(a_s, pWe2, w, l, acc);

  #pragma unroll
  for (int nt = 0; nt < 8; nt++){
    const float b = bs[nt*16 + lr];
    float part = 0.f;
    #pragma unroll
    for (int r = 0; r < 4; r++){
      float v = fmaxf(acc[nt][r] + b, 0.f);
      acc[nt][r] = v; part += v;
    }
    part += __shfl_xor(part, 16);
    part += __shfl_xor(part, 32);
    if (q == 0) atomicAdd(&cs_s[nt*16 + lr], part);
  }
  __syncthreads();                 // all GEMM reads of a_s complete; vmcnt ~0
  // canonical-layout output via XOR-swizzled LDS transpose (2-way conflicts only)
  float* fl = (float*)a_s;
  #pragma unroll
  for (int r = 0; r < 4; r++){
    const int m = w*16 + q*4 + r;
    const int sw = (m & 7) * 4;
    #pragma unroll
    for (int nt = 0; nt < 8; nt++)
      fl[m*128 + ((nt*16 + lr) ^ sw)] = acc[nt][r];
  }
  __syncthreads();                 // LDS-only traffic; vmcnt ~0
  if (t < H2) atomicAdd(&e2p[(blockIdx.x & (NPART-1))*H2 + t], cs_s[t]);
  {
    const int row = t >> 2, c = t & 3;
    const int sw = (row & 7) * 4;
    #pragma unroll
    for (int k = 0; k < 8; k++){
      const int wi = (c*32 + k*4) ^ sw;
      float4 v = *(const float4*)&fl[row*128 + wi];
      *(float4*)&e2f[(e0 + row)*H2 + c*32 + k*4] = v;
    }
  }
}

// ---------------- gathers: mean of rows listed in CSR -> LDS A-tile ----------------
// Indices read directly from lis (wave-uniform broadcast, L2-resident). Depth-8 pipeline:
// one latency exposure covers a mean-degree-8 row.
template<int PITCH>
__device__ __forceinline__ void gather_h1(u16* a_s, const u16* __restrict__ src,
    const int* roff, const int* __restrict__ lis, int w, int l)
{
  for (int rr = 0; rr < 16; rr++){
    int r = w + rr*4;
    int rs = roff[r], re = roff[r+1];
    float s0=0.f, s1=0.f, s2=0.f, s3=0.f;
    int j = rs;
    for (; j + 8 <= re; j += 8){
      int i0=lis[j],i1=lis[j+1],i2=lis[j+2],i3=lis[j+3];
      int i4=lis[j+4],i5=lis[j+5],i6=lis[j+6],i7=lis[j+7];
      usv4 a0 = *(const usv4*)&src[(long)i0*H1 + l*4];
      usv4 a1 = *(const usv4*)&src[(long)i1*H1 + l*4];
      usv4 a2 = *(const usv4*)&src[(long)i2*H1 + l*4];
      usv4 a3 = *(const usv4*)&src[(long)i3*H1 + l*4];
      usv4 a4 = *(const usv4*)&src[(long)i4*H1 + l*4];
      usv4 a5 = *(const usv4*)&src[(long)i5*H1 + l*4];
      usv4 a6 = *(const usv4*)&src[(long)i6*H1 + l*4];
      usv4 a7 = *(const usv4*)&src[(long)i7*H1 + l*4];
      s0 += ((bf2f(a0.x)+bf2f(a1.x)) + (bf2f(a2.x)+bf2f(a3.x)))
          + ((bf2f(a4.x)+bf2f(a5.x)) + (bf2f(a6.x)+bf2f(a7.x)));
      s1 += ((bf2f(a0.y)+bf2f(a1.y)) + (bf2f(a2.y)+bf2f(a3.y)))
          + ((bf2f(a4.y)+bf2f(a5.y)) + (bf2f(a6.y)+bf2f(a7.y)));
      s2 += ((bf2f(a0.z)+bf2f(a1.z)) + (bf2f(a2.z)+bf2f(a3.z)))
          + ((bf2f(a4.z)+bf2f(a5.z)) + (bf2f(a6.z)+bf2f(a7.z)));
      s3 += ((bf2f(a0.w)+bf2f(a1.w)) + (bf2f(a2.w)+bf2f(a3.w)))
          + ((bf2f(a4.w)+bf2f(a5.w)) + (bf2f(a6.w)+bf2f(a7.w)));
    }
    for (; j + 4 <= re; j += 4){
      int i0=lis[j],i1=lis[j+1],i2=lis[j+2],i3=lis[j+3];
      usv4 a0 = *(const usv4*)&src[(long)i0*H1 + l*4];
      usv4 a1 = *(const usv4*)&src[(long)i1*H1 + l*4];
      usv4 a2 = *(const usv4*)&src[(long)i2*H1 + l*4];
      usv4 a3 = *(const usv4*)&src[(long)i3*H1 + l*4];
      s0 += (bf2f(a0.x)+bf2f(a1.x)) + (bf2f(a2.x)+bf2f(a3.x));
      s1 += (bf2f(a0.y)+bf2f(a1.y)) + (bf2f(a2.y)+bf2f(a3.y));
      s2 += (bf2f(a0.z)+bf2f(a1.z)) + (bf2f(a2.z)+bf2f(a3.z));
      s3 += (bf2f(a0.w)+bf2f(a1.w)) + (bf2f(a2.w)+bf2f(a3.w));
    }
    for (; j < re; ++j){
      int i0 = lis[j];
      usv4 a0 = *(const usv4*)&src[(long)i0*H1 + l*4];
      s0 += bf2f(a0.x); s1 += bf2f(a0.y); s2 += bf2f(a0.z); s3 += bf2f(a0.w);
    }
    float rd = 1.f / fmaxf((float)(re - rs), 1.f);
    usv4 o = { f2b(s0*rd), f2b(s1*rd), f2b(s2*rd), f2b(s3*rd) };
    *(usv4*)&a_s[r*PITCH + l*4] = o;
  }
}

template<int PITCH>
__device__ __forceinline__ void gather_h2(u16* a_s, const float* __restrict__ src,
    const int* roff, const int* __restrict__ lis, int w, int l)
{
  for (int rr = 0; rr < 16; rr++){
    int r = w + rr*4;
    int rs = roff[r], re = roff[r+1];
    float s0=0.f, s1=0.f;
    int j = rs;
    for (; j + 8 <= re; j += 8){
      int i0=lis[j],i1=lis[j+1],i2=lis[j+2],i3=lis[j+3];
      int i4=lis[j+4],i5=lis[j+5],i6=lis[j+6],i7=lis[j+7];
      float2 a0 = *(const float2*)&src[(long)i0*H2 + l*2];
      float2 a1 = *(const float2*)&src[(long)i1*H2 + l*2];
      float2 a2 = *(const float2*)&src[(long)i2*H2 + l*2];
      float2 a3 = *(const float2*)&src[(long)i3*H2 + l*2];
      float2 a4 = *(const float2*)&src[(long)i4*H2 + l*2];
      float2 a5 = *(const float2*)&src[(long)i5*H2 + l*2];
      float2 a6 = *(const float2*)&src[(long)i6*H2 + l*2];
      float2 a7 = *(const float2*)&src[(long)i7*H2 + l*2];
      s0 += ((a0.x+a1.x) + (a2.x+a3.x)) + ((a4.x+a5.x) + (a6.x+a7.x));
      s1 += ((a0.y+a1.y) + (a2.y+a3.y)) + ((a4.y+a5.y) + (a6.y+a7.y));
    }
    for (; j + 4 <= re; j += 4){
      int i0=lis[j],i1=lis[j+1],i2=lis[j+2],i3=lis[j+3];
      float2 a0 = *(const float2*)&src[(long)i0*H2 + l*2];
      float2 a1 = *(const float2*)&src[(long)i1*H2 + l*2];
      float2 a2 = *(const float2*)&src[(long)i2*H2 + l*2];
      float2 a3 = *(const float2*)&src[(long)i3*H2 + l*2];
      s0 += (a0.x+a1.x) + (a2.x+a3.x);
      s1 += (a0.y+a1.y) + (a2.y+a3.y);
    }
    for (; j < re; ++j){
      int i0 = lis[j];
      float2 a0 = *(const float2*)&src[(long)i0*H2 + l*2];
      s0 += a0.x; s1 += a0.y;
    }
    float rd = 1.f / fmaxf((float)(re - rs), 1.f);
    usv2 o = { f2b(s0*rd), f2b(s1*rd) };
    *(usv2*)&a_s[r*PITCH + l*2] = o;
  }
}

// ---------------- node block 1 ----------------
// LDS 36.4KB (no index lists) -> 4 blocks/CU; __launch_bounds__(256,4) caps VGPR 128 (need ~80)
__global__ __launch_bounds__(256, 4) void node1_kernel(
    const float* __restrict__ nodes, const u16* __restrict__ e1b,
    const int* __restrict__ off, const int* __restrict__ lis,
    const u16* __restrict__ pWn1, const u16* __restrict__ pWin1, const u16* __restrict__ pWout1,
    const float* __restrict__ bn1, u16* __restrict__ n1b, float* __restrict__ n1p)
{
  __shared__ __align__(16) u16 a_s[64*APK];
  __shared__ int roff[65], roff2[65];
  __shared__ float cs_s[H1];
  __shared__ float bs[H1];
  const int t = threadIdx.x;
  const long n0 = (long)blockIdx.x * 64;
  const int w = t >> 6, l = t & 63, lr = l & 15, q = l >> 4;

  cs_s[t] = 0.f;
  bs[t] = bn1[t];
  if (t <= 64){
    long idx = n0 + t;
    roff [t] = (idx >= NN) ? NE     : off[idx];
    roff2[t] = (idx >= NN) ? 2*NE   : off[NN + idx];
  }
  __syncthreads();

  f32v4 acc[16];
  #pragma unroll
  for (int nt = 0; nt < 16; nt++) acc[nt] = (f32v4){0.f,0.f,0.f,0.f};

  gather_h1<APK>(a_s, e1b, roff, lis, w, l);
  __syncthreads();
  gemm_tiles<8,16,APK>(a_s, pWin1, w, l, acc);
  __syncthreads();

  gather_h1<APK>(a_s, e1b, roff2, lis, w, l);
  __syncthreads();
  gemm_tiles<8,16,APK>(a_s, pWout1, w, l, acc);
  __syncthreads();

  stage_rows<3>(a_s, nodes, n0, t);
  __syncthreads();
  gemm_tiles<1,16,APK>(a_s, pWn1, w, l, acc);

  #pragma unroll
  for (int nt = 0; nt < 16; nt++){
    const float b = bs[nt*16 + lr];
    float part = 0.f;
    #pragma unroll
    for (int r = 0; r < 4; r++){
      const long n = n0 + w*16 + q*4 + r;
      float v = fmaxf(acc[nt][r] + b, 0.f);
      acc[nt][r] = v;
      if (n < NN) part += v;
    }
    part += __shfl_xor(part, 16);
    part += __shfl_xor(part, 32);
    if (q == 0) atomicAdd(&cs_s[nt*16 + lr], part);
  }
  __syncthreads();                  // vmcnt ~0: n1b stores NOT issued yet
  atomicAdd(&n1p[(blockIdx.x & (NPART-1))*H1 + t], cs_s[t]);
  // bulk stores LAST
  #pragma unroll
  for (int r = 0; r < 4; r++){
    const int m = w*16 + q*4 + r;
    const long n = n0 + m;
    if (n < NN){
      usv8 o0, o1;
      #pragma unroll
      for (int h = 0; h < 8; h++){ o0[h] = f2b(acc[h][r]); o1[h] = f2b(acc[8+h][r]); }
      *(usv8*)&n1b[n*H1 + lr*16]     = o0;
      *(usv8*)&n1b[n*H1 + lr*16 + 8] = o1;
    }
  }
}

// ---------------- node block 2 ----------------
__global__ __launch_bounds__(256, 4) void node2_kernel(
    const u16* __restrict__ n1b, const float* __restrict__ e2f,
    const int* __restrict__ off, const int* __restrict__ lis,
    const u16* __restrict__ pWn2, const u16* __restrict__ pWin2, const u16* __restrict__ pWout2,
    const float* __restrict__ bn2, float* __restrict__ n2_out, float* __restrict__ n2p)
{
  __shared__ __align__(16) u16 a_s[64*AP2];
  __shared__ int roff[65], roff2[65];
  __shared__ float cs_s[H2];
  const int t = threadIdx.x;
  const long n0 = (long)blockIdx.x * 64;
  const int w = t >> 6, l = t & 63, lr = l & 15, q = l >> 4;

  if (t < H2) cs_s[t] = 0.f;
  if (t <= 64){
    long idx = n0 + t;
    roff [t] = (idx >= NN) ? NE     : off[idx];
    roff2[t] = (idx >= NN) ? 2*NE   : off[NN + idx];
  }
  __syncthreads();

  f32v4 acc[8];
  #pragma unroll
  for (int nt = 0; nt < 8; nt++) acc[nt] = (f32v4){0.f,0.f,0.f,0.f};

  // A = n1 (permuted bf16 rows), K=256 as two K=128 half-tiles; pWn2 packed with g1
  for (int h = 0; h < 2; h++){
    for (int idx = t; idx < 64*16; idx += 256){
      int row = idx >> 4, ch = idx & 15;
      long n = n0 + row;
      usv8 v = (usv8){0,0,0,0,0,0,0,0};
      if (n < NN) v = *(const usv8*)&n1b[n*H1 + h*128 + ch*8];
      *(usv8*)&a_s[row*AP2 + ch*8] = v;
    }
    __syncthreads();
    gemm_tiles<4,8,AP2>(a_s, pWn2 + h*(4*8*64*8), w, l, acc);
    __syncthreads();
  }

  gather_h2<AP2>(a_s, e2f, roff, lis, w, l);
  __syncthreads();
  gemm_tiles<4,8,AP2>(a_s, pWin2, w, l, acc);
  __syncthreads();

  gather_h2<AP2>(a_s, e2f, roff2, lis, w, l);
  __syncthreads();
  gemm_tiles<4,8,AP2>(a_s, pWout2, w, l, acc);

  #pragma unroll
  for (int nt = 0; nt < 8; nt++){
    const float b = bn2[nt*16 + lr];
    float part = 0.f;
    #pragma unroll
    for (int r = 0; r < 4; r++){
      const long n = n0 + w*16 + q*4 + r;
      float v = fmaxf(acc[nt][r] + b, 0.f);
      acc[nt][r] = v;
      if (n < NN) part += v;
    }
    part += __shfl_xor(part, 16);
    part += __shfl_xor(part, 32);
    if (q == 0) atomicAdd(&cs_s[nt*16 + lr], part);
  }
  __syncthreads();                  // vmcnt ~0: n2 stores NOT issued yet
  if (t < H2) atomicAdd(&n2p[(blockIdx.x & (NPART-1))*H2 + t], cs_s[t]);
  // stores LAST
  #pragma unroll
  for (int nt = 0; nt < 8; nt++){
    const int j = nt*16 + lr;
    #pragma unroll
    for (int r = 0; r < 4; r++){
      const long n = n0 + w*16 + q*4 + r;
      if (n < NN) n2_out[n*H2 + j] = acc[nt][r];
    }
  }
}

// ---------------- global updates (reduce NPART partial copies, then tiny GEMV) ----------------
__global__ void u1_kernel(const float* __restrict__ gu, const float* __restrict__ Wu1,
    const float* __restrict__ Wgn1, const float* __restrict__ Wge1, const float* __restrict__ bu1,
    const float* __restrict__ n1p, const float* __restrict__ e1p, float* __restrict__ u1v)
{
    __shared__ float ncs[H1], ecs[H1];
    const int j = threadIdx.x;
    float sn = 0.f, se = 0.f;
    #pragma unroll 8
    for (int c = 0; c < NPART; c++){ sn += n1p[c*H1 + j]; se += e1p[c*H1 + j]; }
    ncs[j] = sn; ecs[j] = se;
    __syncthreads();
    float acc = bu1[j];
    #pragma unroll
    for (int k = 0; k < FG; k++) acc += gu[k] * Wu1[k*H1 + j];
    for (int k = 0; k < H1; k++) acc += (ncs[k] * (1.f/NN)) * Wgn1[k*H1 + j];
    for (int k = 0; k < H1; k++) acc += (ecs[k] * (1.f/NE)) * Wge1[k*H1 + j];
    u1v[j] = fmaxf(acc, 0.f);
}

__global__ void u2_kernel(const float* __restrict__ u1v, const float* __restrict__ Wu2,
    const float* __restrict__ Wgn2, const float* __restrict__ Wge2, const float* __restrict__ bu2,
    const float* __restrict__ n2p, const float* __restrict__ e2p, float* __restrict__ u2_out)
{
    __shared__ float ncs[H2], ecs[H2];
    const int j = threadIdx.x;
    float sn = 0.f, se = 0.f;
    #pragma unroll 8
    for (int c = 0; c < NPART; c++){ sn += n2p[c*H2 + j]; se += e2p[c*H2 + j]; }
    ncs[j] = sn; ecs[j] = se;
    __syncthreads();
    float acc = bu2[j];
    for (int k = 0; k < H1; k++) acc += u1v[k] * Wu2[k*H2 + j];
    for (int k = 0; k < H2; k++) acc += (ncs[k] * (1.f/NN)) * Wgn2[k*H2 + j];
    for (int k = 0; k < H2; k++) acc += (ecs[k] * (1.f/NE)) * Wge2[k*H2 + j];
    u2_out[j] = fmaxf(acc, 0.f);
}

// ---------------- launcher ----------------
extern "C" void kernel_launch(void* const* d_in, const int* in_sizes, int n_in,
                              void* d_out, int out_size, void* d_ws, size_t ws_size,
                              hipStream_t stream)
{
    (void)in_sizes; (void)n_in; (void)out_size; (void)ws_size;
    const float* nodes = (const float*)d_in[0];
    const float* edges = (const float*)d_in[1];
    const float* gu    = (const float*)d_in[2];
    const int* senders   = (const int*)d_in[3];
    const int* receivers = (const int*)d_in[4];
    const float* We1  = (const float*)d_in[5];  const float* be1 = (const float*)d_in[6];
    const float* Wn1  = (const float*)d_in[7];  const float* Win1= (const float*)d_in[8];
    const float* Wout1= (const float*)d_in[9];  const float* bn1 = (const float*)d_in[10];
    const float* Wu1  = (const float*)d_in[11]; const float* Wgn1= (const float*)d_in[12];
    const float* Wge1 = (const float*)d_in[13]; const float* bu1 = (const float*)d_in[14];
    const float* We2  = (const float*)d_in[15]; const float* be2 = (const float*)d_in[16];
    const float* Wn2  = (const float*)d_in[17]; const float* Win2= (const float*)d_in[18];
    const float* Wout2= (const float*)d_in[19]; const float* bn2 = (const float*)d_in[20];
    const float* Wu2  = (const float*)d_in[21]; const float* Wgn2= (const float*)d_in[22];
    const float* Wge2 = (const float*)d_in[23]; const float* bu2 = (const float*)d_in[24];

    float* ws = (float*)d_ws;
    size_t o = 0;
    int*   cnt    = (int*)(ws + o);  o += M2;            // zeroed
    float* e1p    = ws + o;          o += (size_t)NPART*H1;  // zeroed
    float* n1p    = ws + o;          o += (size_t)NPART*H1;  // zeroed
    float* e2p    = ws + o;          o += (size_t)NPART*H2;  // zeroed
    float* n2p    = ws + o;          o += (size_t)NPART*H2;  // zeroed
    const size_t zero_bytes = o * sizeof(float);
    float* u1v    = ws + o;          o += 256;
    int*   off    = (int*)(ws + o);  o += M2;
    int*   pos_in = (int*)(ws + o);  o += NE;
    int*   pos_out= (int*)(ws + o);  o += NE;
    int*   lis    = (int*)(ws + o);  o += 2*NE;
    int*   btot   = (int*)(ws + o);  o += 400;

    u16* pbase = (u16*)(ws + o);
    size_t po = 0;
    u16* pWin1 = pbase + po;  po += (size_t)H1*H1;
    u16* pWout1= pbase + po;  po += (size_t)H1*H1;
    u16* pWn1  = pbase + po;  po += (size_t)FN*H1;
    u16* pWe1  = pbase + po;  po += (size_t)32*H1;   // K padded 16->32
    u16* pWe2  = pbase + po;  po += (size_t)H1*H2;
    u16* pWn2  = pbase + po;  po += (size_t)H1*H2;
    u16* pWin2 = pbase + po;  po += (size_t)H2*H2;
    u16* pWout2= pbase + po;  po += (size_t)H2*H2;
    o += (po + 1) / 2;

    u16* n1b = (u16*)(ws + o);       // NN*H1 bf16 = 25.6 MB (permuted cols)

    float* n2_out = (float*)d_out;
    float* e2f    = n2_out + (size_t)NN*H2;          // e2 region; also scratch for e1 (bf16)
    float* u2_out = n2_out + (size_t)(NN + NE)*H2;
    u16*   e1b    = (u16*)e2f;                       // e1 bf16 rows (permuted cols) until e2_kernel

    hipMemsetAsync(d_ws, 0, zero_bytes, stream);

    PackArgs pa;
    pa.d[0] = {Win1,  pWin1,  H1, H1, H1, 1};
    pa.d[1] = {Wout1, pWout1, H1, H1, H1, 1};
    pa.d[2] = {Wn1,   pWn1,   FN, H1, FN, 0};
    pa.d[3] = {We1,   pWe1,   32, H1, FE, 0};
    pa.d[4] = {We2,   pWe2,   H1, H2, H1, 1};
    pa.d[5] = {Wn2,   pWn2,   H1, H2, H1, 1};
    pa.d[6] = {Win2,  pWin2,  H2, H2, H2, 0};   // gather_h2 A-tile is CANONICAL -> no perm
    pa.d[7] = {Wout2, pWout2, H2, H2, H2, 0};   // gather_h2 A-tile is CANONICAL -> no perm
    int total_tiles = 0;
    for (int i = 0; i < 8; i++) total_tiles += (pa.d[i].K >> 5) * (pa.d[i].N >> 4);
    pack_weights<<<total_tiles, 64, 0, stream>>>(pa);

    const int EG = (NE + 255)/256;
    csr_count<<<EG, 256, 0, stream>>>(receivers, senders, cnt, pos_in, pos_out);
    scan_blocks<<<SCAN_B, 256, 0, stream>>>(cnt, off, btot);
    scan_tops<<<1, 256, 0, stream>>>(btot);
    scan_fix<<<SCAN_B, 256, 0, stream>>>(off, btot);
    csr_fill<<<EG, 256, 0, stream>>>(receivers, senders, off, pos_in, pos_out, lis);

    edge1_kernel<<<NE/64, 256, 0, stream>>>(edges, pWe1, be1, e1b, e1p);

    node1_kernel<<<(NN + 63)/64, 256, 0, stream>>>(nodes, e1b, off, lis,
        pWn1, pWin1, pWout1, bn1, n1b, n1p);

    u1_kernel<<<1, H1, 0, stream>>>(gu, Wu1, Wgn1, Wge1, bu1, n1p, e1p, u1v);

    e2_kernel<<<NE/64, 256, 0, stream>>>(e2f, pWe2, be2, e2p);

    node2_kernel<<<(NN + 63)/64, 256, 0, stream>>>(n1b, e2f, off, lis,
        pWn2, pWin2, pWout2, bn2, n2_out, n2p);

    u2_kernel<<<1, H2, 0, stream>>>(u1v, Wu2, Wgn2, Wge2, bu2, n2p, e2p, u2_out);
}